// Round 1
// baseline (727.531 us; speedup 1.0000x reference)
//
#include <hip/hip_runtime.h>
#include <hip/hip_bf16.h>
#include <cmath>

#define BDIM 8
#define HDIM 256
#define LDIM 4096
#define NDIM 64

// ---------------------------------------------------------------------------
// Kernel 1: diagonal complex SSM scan, one wave per (b,h) sequence.
// y[b,h,l] = tanh( 2*Re(sum_n CB_n * x_n[l]) + D[h]*u[l] ),
// x_n[l] = Lam_n * x_n[l-1] + u[l]
// Written into d_out (reused as scratch for the mix kernel).
// ---------------------------------------------------------------------------
__global__ __launch_bounds__(256) void scan_kernel(
    const float* __restrict__ u,
    const float* __restrict__ lre_g, const float* __restrict__ lim_g,
    const float* __restrict__ cbre_g, const float* __restrict__ cbim_g,
    const float* __restrict__ Dg,
    float* __restrict__ y)
{
    const int wave = threadIdx.x >> 6;
    const int lane = threadIdx.x & 63;
    const int seq  = blockIdx.x * 4 + wave;      // 0..B*H-1
    const int h    = seq & (HDIM - 1);

    const float lre  = lre_g[h * NDIM + lane];
    const float lim  = lim_g[h * NDIM + lane];
    const float cbre = 2.0f * cbre_g[h * NDIM + lane];
    const float cbim = 2.0f * cbim_g[h * NDIM + lane];
    const float Dh   = Dg[h];

    const float* up = u + (size_t)seq * LDIM;
    float*       yp = y + (size_t)seq * LDIM;

    float xre = 0.0f, xim = 0.0f;

    for (int l0 = 0; l0 < LDIM; l0 += 64) {
        const float uc = up[l0 + lane];           // coalesced chunk load
        float yreg = 0.0f;
        #pragma unroll
        for (int t = 0; t < 64; ++t) {
            const float ut = __shfl(uc, t);       // broadcast u[l0+t]
            // x = Lam*x + u   (complex)
            float nre = fmaf(lre, xre, ut);
            nre = fmaf(-lim, xim, nre);
            float nim = lre * xim;
            nim = fmaf(lim, xre, nim);
            xre = nre; xim = nim;
            // contribution 2*Re(CB * x)  (2x folded into cbre/cbim)
            float c = cbre * xre;
            c = fmaf(-cbim, xim, c);
            // full-wave butterfly sum over n
            #pragma unroll
            for (int m = 32; m > 0; m >>= 1) c += __shfl_xor(c, m);
            if (lane == t) yreg = c;              // lane t owns step l0+t
        }
        yp[l0 + lane] = tanhf(fmaf(Dh, uc, yreg));
    }
}

// ---------------------------------------------------------------------------
// Kernel 2: transpose W_mix [512][256] -> Wt [256][512] for coalesced reads
// ---------------------------------------------------------------------------
__global__ __launch_bounds__(256) void transpose_w(
    const float* __restrict__ W, float* __restrict__ Wt)
{
    const int idx = blockIdx.x * 256 + threadIdx.x;  // 131072 total
    const int o  = idx & 511;
    const int hp = idx >> 9;
    Wt[hp * 512 + o] = W[o * 256 + hp];
}

// ---------------------------------------------------------------------------
// Kernel 3: channel mix (z = W y + b) + GLU.  Reads y from d_out, writes
// result into the same (b, l-tile) slice of d_out (barrier between).
// block = 256 threads; thread h owns output rows h (a) and h+256 (g),
// 32 consecutive l per block.
// ---------------------------------------------------------------------------
__global__ __launch_bounds__(256) void mix_kernel(
    float* __restrict__ y,                 // aliases out
    const float* __restrict__ Wt,          // [256][512]
    const float* __restrict__ bm,          // [512]
    float* __restrict__ out)
{
    const int h  = threadIdx.x;            // 0..255
    const int b  = blockIdx.y;
    const int l0 = blockIdx.x * 32;

    const float* ybase = y + ((size_t)b * HDIM) * LDIM + l0;

    float acc_a[32], acc_g[32];
    const float ba = bm[h], bg = bm[h + 256];
    #pragma unroll
    for (int j = 0; j < 32; ++j) { acc_a[j] = ba; acc_g[j] = bg; }

    for (int hp = 0; hp < HDIM; ++hp) {
        const float wa = Wt[hp * 512 + h];
        const float wg = Wt[hp * 512 + 256 + h];
        const float* yr = ybase + (size_t)hp * LDIM;
        #pragma unroll
        for (int j = 0; j < 32; ++j) {
            const float yv = yr[j];        // wave-uniform broadcast
            acc_a[j] = fmaf(wa, yv, acc_a[j]);
            acc_g[j] = fmaf(wg, yv, acc_g[j]);
        }
    }

    __syncthreads();   // all reads of the y slice done before overwriting it

    float* op = out + ((size_t)b * HDIM + h) * LDIM + l0;
    #pragma unroll
    for (int j = 0; j < 32; ++j) {
        const float g = acc_g[j];
        const float s = 1.0f / (1.0f + __expf(-g));
        op[j] = acc_a[j] * s;
    }
}

// ---------------------------------------------------------------------------
extern "C" void kernel_launch(void* const* d_in, const int* in_sizes, int n_in,
                              void* d_out, int out_size, void* d_ws, size_t ws_size,
                              hipStream_t stream)
{
    const float* u    = (const float*)d_in[0];
    const float* lre  = (const float*)d_in[1];
    const float* lim  = (const float*)d_in[2];
    const float* cbre = (const float*)d_in[3];
    const float* cbim = (const float*)d_in[4];
    const float* Dg   = (const float*)d_in[5];
    const float* W    = (const float*)d_in[6];
    const float* bm   = (const float*)d_in[7];
    float* out = (float*)d_out;
    float* Wt  = (float*)d_ws;             // 256*512*4 = 512 KB

    // W transpose (independent of scan; same stream serializes anyway)
    transpose_w<<<512, 256, 0, stream>>>(W, Wt);

    // SSM scan -> y (stored in d_out as scratch)
    scan_kernel<<<(BDIM * HDIM) / 4, 256, 0, stream>>>(u, lre, lim, cbre, cbim, Dg, out);

    // mix + GLU (in-place on d_out, per-(b,l)-slice)
    dim3 grid(LDIM / 32, BDIM);
    mix_kernel<<<grid, 256, 0, stream>>>(out, Wt, bm, out);
}

// Round 2
// 346.231 us; speedup vs baseline: 2.1013x; 2.1013x over previous
//
#include <hip/hip_runtime.h>
#include <hip/hip_bf16.h>
#include <cmath>

#define BDIM 8
#define HDIM 256
#define LDIM 4096
#define NDIM 64
#define TCH  64               // chunk length
#define NCH  (LDIM / TCH)     // 64 chunks

__device__ __forceinline__ float rcp_fast(float x) {
    return __builtin_amdgcn_rcpf(x);
}
__device__ __forceinline__ float tanh_fast(float x) {
    // tanh(x) = 1 - 2/(e^{2x}+1); saturates correctly at +-inf
    float e = __expf(2.0f * x);
    return 1.0f - 2.0f * rcp_fast(e + 1.0f);
}

// ---------------------------------------------------------------------------
// Phase 0: per-h tables.
//   K[h][d]    = 2*Re(sum_n CB_n Lam_n^d),        d = 0..63   (real)
//   G[h][n][t] = 2*CB_n*Lam_n^{t+1},              t = 0..63   (complex)
//   P[h][s][n] = Lam_n^{63-s},                    s = 0..63   (complex)
// One wave per h.
// ---------------------------------------------------------------------------
__global__ __launch_bounds__(64) void tables_kernel(
    const float* __restrict__ lre_g, const float* __restrict__ lim_g,
    const float* __restrict__ cbre_g, const float* __restrict__ cbim_g,
    float2* __restrict__ Gt,   // [H][N][T]
    float2* __restrict__ Pt,   // [H][T][N]
    float*  __restrict__ Kt)   // [H][T]
{
    const int h = blockIdx.x;
    const int n = threadIdx.x;          // lane = state index
    const float lr = lre_g[h * NDIM + n], li = lim_g[h * NDIM + n];
    const float cr = 2.0f * cbre_g[h * NDIM + n];
    const float ci = 2.0f * cbim_g[h * NDIM + n];

    float2* Gh = Gt + (size_t)h * NDIM * TCH + (size_t)n * TCH;
    float2* Ph = Pt + (size_t)h * TCH * NDIM;

    float qr = 1.0f, qi = 0.0f;         // Lam^t
    for (int t = 0; t < TCH; ++t) {
        // K[t] = sum_n Re(cb2 * Lam^t)
        float kp = cr * qr - ci * qi;
        #pragma unroll
        for (int m = 32; m > 0; m >>= 1) kp += __shfl_xor(kp, m);
        if (n == 0) Kt[h * TCH + t] = kp;
        // P[63-t][n] = Lam^t
        Ph[(63 - t) * NDIM + n] = make_float2(qr, qi);
        // q <- Lam^{t+1}
        float nqr = qr * lr - qi * li;
        float nqi = qr * li + qi * lr;
        qr = nqr; qi = nqi;
        // G[n][t] = cb2 * Lam^{t+1}
        Gh[t] = make_float2(cr * qr - ci * qi, cr * qi + ci * qr);
    }
}

// ---------------------------------------------------------------------------
// Phase 1: chunked scan. Block = 512 threads = 8 waves, one h per block,
// wave w handles batch b = w. No cross-lane ops in the chunk loop.
// y written to d_out (scratch for the mix kernel).
// ---------------------------------------------------------------------------
__global__ __launch_bounds__(512) void scan2_kernel(
    const float* __restrict__ u,
    const float* __restrict__ Dg,
    const float2* __restrict__ Gt,
    const float2* __restrict__ Pt,
    const float* __restrict__ Kt,
    float* __restrict__ y)
{
    __shared__ float4 Gl4[NDIM * TCH / 2];   // 32 KB : G[h] as float2[64][64]
    __shared__ float4 Pl4[TCH * NDIM / 2];   // 32 KB : P[h] as float2[64][64]
    __shared__ float  ush[BDIM][2 * TCH];    // 4 KB  : zero-pad + u chunk per wave
    __shared__ float2 xsh[BDIM][NDIM];       // 4 KB  : chunk-start state per wave

    const int h    = blockIdx.x;
    const int w    = threadIdx.x >> 6;       // wave index = batch b
    const int lane = threadIdx.x & 63;

    // cooperative table loads (each 2048 float4)
    const float4* Gsrc = (const float4*)(Gt + (size_t)h * NDIM * TCH);
    const float4* Psrc = (const float4*)(Pt + (size_t)h * TCH * NDIM);
    #pragma unroll
    for (int i = 0; i < 4; ++i) {
        Gl4[threadIdx.x + i * 512] = Gsrc[threadIdx.x + i * 512];
        Pl4[threadIdx.x + i * 512] = Psrc[threadIdx.x + i * 512];
    }
    ush[w][lane] = 0.0f;                     // zero pad for causal conv
    __syncthreads();

    const float2* Gl = (const float2*)Gl4;   // [n][t]
    const float2* Pl = (const float2*)Pl4;   // [s][n]
    const float* Kh = Kt + h * TCH;          // uniform -> scalar loads
    const float Dh = Dg[h];

    // LT = Lam^64 per lane (6 squarings of per-lane Lam read from P[62][n]=Lam^1)
    float2 lam1 = Pl[62 * NDIM + lane];      // Lam^1
    float ltr = lam1.x, lti = lam1.y;
    #pragma unroll
    for (int i = 0; i < 6; ++i) {
        float nr = ltr * ltr - lti * lti;
        float ni = 2.0f * ltr * lti;
        ltr = nr; lti = ni;
    }

    const float* up = u + ((size_t)w * HDIM + h) * LDIM;
    float*       yp = y + ((size_t)w * HDIM + h) * LDIM;

    float xr = 0.0f, xi = 0.0f;              // state at chunk start
    float ucur = up[lane];

    for (int c = 0; c < NCH; ++c) {
        ush[w][TCH + lane] = ucur;
        xsh[w][lane] = make_float2(xr, xi);
        // prefetch next chunk's u (wraps harmlessly on last iter)
        float unext = up[((c + 1) & (NCH - 1)) * TCH + lane];
        __builtin_amdgcn_wave_barrier();     // order LDS writes before reads (same wave)

        // ---- within-chunk causal conv: lane t: sum_d K[d]*u[t-d] ----
        float a0 = 0.0f, a1 = 0.0f;
        #pragma unroll
        for (int d = 0; d < TCH; d += 2) {
            a0 = fmaf(Kh[d],     ush[w][TCH + lane - d],     a0);
            a1 = fmaf(Kh[d + 1], ush[w][TCH + lane - d - 1], a1);
        }

        // ---- carry: lane t: Re(sum_n G[n][t] * x_n) ----
        float b0 = 0.0f, b1 = 0.0f, b2 = 0.0f, b3 = 0.0f;
        #pragma unroll
        for (int n = 0; n < NDIM; n += 2) {
            float2 g0 = Gl[n * TCH + lane];
            float2 s0 = xsh[w][n];
            b0 = fmaf(g0.x, s0.x, b0);
            b1 = fmaf(-g0.y, s0.y, b1);
            float2 g1 = Gl[(n + 1) * TCH + lane];
            float2 s1 = xsh[w][n + 1];
            b2 = fmaf(g1.x, s1.x, b2);
            b3 = fmaf(-g1.y, s1.y, b3);
        }

        // ---- v = sum_s Lam^{63-s} u[s]  (lane = n) ----
        float vr0 = 0.0f, vi0 = 0.0f, vr1 = 0.0f, vi1 = 0.0f;
        #pragma unroll
        for (int s = 0; s < TCH; s += 2) {
            float us0 = ush[w][TCH + s];
            float2 ps0 = Pl[s * NDIM + lane];
            vr0 = fmaf(ps0.x, us0, vr0);
            vi0 = fmaf(ps0.y, us0, vi0);
            float us1 = ush[w][TCH + s + 1];
            float2 ps1 = Pl[(s + 1) * NDIM + lane];
            vr1 = fmaf(ps1.x, us1, vr1);
            vi1 = fmaf(ps1.y, us1, vi1);
        }
        float vr = vr0 + vr1, vi = vi0 + vi1;

        // ---- state update: x <- Lam^64 * x + v ----
        float nxr = fmaf(ltr, xr, fmaf(-lti, xi, vr));
        float nxi = fmaf(ltr, xi, fmaf( lti, xr, vi));

        // ---- output ----
        float yt = (a0 + a1) + (b0 + b1) + (b2 + b3);
        yp[c * TCH + lane] = tanh_fast(fmaf(Dh, ucur, yt));

        xr = nxr; xi = nxi;
        ucur = unext;
        __builtin_amdgcn_wave_barrier();     // reads done before next chunk's writes
    }
}

// ---------------------------------------------------------------------------
// W transpose: [512][256] -> [256][512]
// ---------------------------------------------------------------------------
__global__ __launch_bounds__(256) void transpose_w(
    const float* __restrict__ W, float* __restrict__ Wt)
{
    const int idx = blockIdx.x * 256 + threadIdx.x;
    const int o  = idx & 511;
    const int hp = idx >> 9;
    Wt[hp * 512 + o] = W[o * 256 + hp];
}

// ---------------------------------------------------------------------------
// Mix + GLU, in-place on d_out per (b, l-tile) slice.
// ---------------------------------------------------------------------------
__global__ __launch_bounds__(256) void mix_kernel(
    float* __restrict__ y,                 // aliases out
    const float* __restrict__ Wt,          // [256][512]
    const float* __restrict__ bm,          // [512]
    float* __restrict__ out)
{
    const int h  = threadIdx.x;
    const int b  = blockIdx.y;
    const int l0 = blockIdx.x * 32;

    const float* ybase = y + ((size_t)b * HDIM) * LDIM + l0;

    float acc_a[32], acc_g[32];
    const float ba = bm[h], bg = bm[h + 256];
    #pragma unroll
    for (int j = 0; j < 32; ++j) { acc_a[j] = ba; acc_g[j] = bg; }

    for (int hp = 0; hp < HDIM; ++hp) {
        const float wa = Wt[hp * 512 + h];
        const float wg = Wt[hp * 512 + 256 + h];
        const float* yr = ybase + (size_t)hp * LDIM;
        #pragma unroll
        for (int j = 0; j < 32; ++j) {
            const float yv = yr[j];
            acc_a[j] = fmaf(wa, yv, acc_a[j]);
            acc_g[j] = fmaf(wg, yv, acc_g[j]);
        }
    }

    __syncthreads();

    float* op = out + ((size_t)b * HDIM + h) * LDIM + l0;
    #pragma unroll
    for (int j = 0; j < 32; ++j) {
        const float g = acc_g[j];
        const float s = rcp_fast(1.0f + __expf(-g));
        op[j] = acc_a[j] * s;
    }
}

// ---------------------------------------------------------------------------
extern "C" void kernel_launch(void* const* d_in, const int* in_sizes, int n_in,
                              void* d_out, int out_size, void* d_ws, size_t ws_size,
                              hipStream_t stream)
{
    const float* u    = (const float*)d_in[0];
    const float* lre  = (const float*)d_in[1];
    const float* lim  = (const float*)d_in[2];
    const float* cbre = (const float*)d_in[3];
    const float* cbim = (const float*)d_in[4];
    const float* Dg   = (const float*)d_in[5];
    const float* W    = (const float*)d_in[6];
    const float* bm   = (const float*)d_in[7];
    float* out = (float*)d_out;

    // workspace layout
    char* ws = (char*)d_ws;
    float*  Wt = (float*)ws;                               // 512 KB
    float2* Gt = (float2*)(ws + (1 << 19));                // 8 MB
    float2* Pt = (float2*)(ws + (1 << 19) + (1 << 23));    // 8 MB
    float*  Kt = (float*)(ws + (1 << 19) + (2 << 23));     // 64 KB

    tables_kernel<<<HDIM, NDIM, 0, stream>>>(lre, lim, cbre, cbim, Gt, Pt, Kt);
    transpose_w<<<512, 256, 0, stream>>>(W, Wt);
    scan2_kernel<<<HDIM, 512, 0, stream>>>(u, Dg, Gt, Pt, Kt, out);
    dim3 grid(LDIM / 32, BDIM);
    mix_kernel<<<grid, 256, 0, stream>>>(out, Wt, bm, out);
}

// Round 3
// 241.199 us; speedup vs baseline: 3.0163x; 1.4355x over previous
//
#include <hip/hip_runtime.h>
#include <hip/hip_bf16.h>
#include <cmath>

#define BDIM 8
#define HDIM 256
#define LDIM 4096
#define NDIM 64
#define TCH  64
#define NCH  64

typedef unsigned short u16;
typedef __attribute__((ext_vector_type(8))) short short8x;
typedef __attribute__((ext_vector_type(4))) float f32x4;
typedef __attribute__((ext_vector_type(4))) unsigned short ushort4x;

__device__ __forceinline__ float rcp_fast(float x) { return __builtin_amdgcn_rcpf(x); }
__device__ __forceinline__ float tanh_fast(float x) {
    float e = __expf(2.0f * x);
    return 1.0f - 2.0f * rcp_fast(e + 1.0f);
}
__device__ __forceinline__ u16 f2bf(float f) {
    unsigned int u = __float_as_uint(f);
    u = u + 0x7fffu + ((u >> 16) & 1u);
    return (u16)(u >> 16);
}
__device__ __forceinline__ float bf2f(u16 s) {
    return __uint_as_float(((unsigned int)s) << 16);
}

// ---------------------------------------------------------------------------
// Tables (one wave per h):
//  P_stack [128 rows(n' = n re / n+64 im)][64 s]  = Lam_n^{63-s}      (bf16 hi/lo)
//  G_stack [64 t][128 n']: [n]=2Re(CB Lam^{t+1}), [n+64]=-2Im(...)    (bf16 hi/lo)
//  T       [64 t][64 s] = K[t-s] (t>=s), K[d]=2Re(sum CB Lam^d)       (bf16 hi/lo)
//  L64     [n] = Lam_n^64                                             (f32)
// ---------------------------------------------------------------------------
__global__ __launch_bounds__(64) void tables2_kernel(
    const float* __restrict__ lre_g, const float* __restrict__ lim_g,
    const float* __restrict__ cbre_g, const float* __restrict__ cbim_g,
    u16* __restrict__ Phi, u16* __restrict__ Plo,
    u16* __restrict__ Ghi, u16* __restrict__ Glo,
    u16* __restrict__ Thi, u16* __restrict__ Tlo,
    float2* __restrict__ L64)
{
    __shared__ float Ksh[64];
    const int h = blockIdx.x, n = threadIdx.x;
    const float lr = lre_g[h * 64 + n], li = lim_g[h * 64 + n];
    const float cr = 2.0f * cbre_g[h * 64 + n];
    const float ci = 2.0f * cbim_g[h * 64 + n];

    u16* Ph = Phi + (size_t)h * 8192; u16* Pl = Plo + (size_t)h * 8192;
    u16* Gh = Ghi + (size_t)h * 8192; u16* Gl = Glo + (size_t)h * 8192;
    u16* Th = Thi + (size_t)h * 4096; u16* Tl = Tlo + (size_t)h * 4096;

    float qr = 1.0f, qi = 0.0f;                      // Lam^t
    for (int t = 0; t < 64; ++t) {
        float kp = cr * qr - ci * qi;                // 2Re(CB Lam^t)
        #pragma unroll
        for (int m = 32; m > 0; m >>= 1) kp += __shfl_xor(kp, m);
        if (n == 0) Ksh[t] = kp;

        int sre = n * 64 + (63 - t), sim = (n + 64) * 64 + (63 - t);
        u16 hre = f2bf(qr); Ph[sre] = hre; Pl[sre] = f2bf(qr - bf2f(hre));
        u16 him = f2bf(qi); Ph[sim] = him; Pl[sim] = f2bf(qi - bf2f(him));

        float nqr = qr * lr - qi * li;               // Lam^{t+1}
        float nqi = qr * li + qi * lr;
        qr = nqr; qi = nqi;

        float gre = cr * qr - ci * qi;               // 2Re(CB Lam^{t+1})
        float gim = cr * qi + ci * qr;               // 2Im(...)
        int o1 = t * 128 + n, o2 = o1 + 64;
        u16 g1 = f2bf(gre);  Gh[o1] = g1; Gl[o1] = f2bf(gre - bf2f(g1));
        float ngim = -gim;
        u16 g2 = f2bf(ngim); Gh[o2] = g2; Gl[o2] = f2bf(ngim - bf2f(g2));
    }
    L64[h * 64 + n] = make_float2(qr, qi);           // Lam^64
    __syncthreads();
    for (int r = 0; r < 64; ++r) {
        float val = (n <= r) ? Ksh[r - n] : 0.0f;
        u16 hv = f2bf(val);
        Th[r * 64 + n] = hv; Tl[r * 64 + n] = f2bf(val - bf2f(hv));
    }
}

// ---------------------------------------------------------------------------
// MFMA chunked scan: one block per (b,h), 4 waves, wave w owns cols 16w..16w+15.
//   V[n'][c] = sum_s P[n'][s] u[64c+s]          (MFMA)
//   X[c+1]   = Lam64*X[c] + V[:,c]              (serial, wave 0, 64 steps)
//   Y[t][c]  = G_stack.X[:,c] + T.u_c           (MFMA, accumulated)
//   y        = tanh(Y + D*u)                    (epilogue)
// LDS 80KB -> 2 blocks/CU. All LDS tiles XOR-swizzled (byte ^= (c&7)<<4).
// ---------------------------------------------------------------------------
__global__ __launch_bounds__(256) void scan3_kernel(
    const float* __restrict__ u,
    const float* __restrict__ Dg,
    const u16* __restrict__ Phi, const u16* __restrict__ Plo,
    const u16* __restrict__ Ghi, const u16* __restrict__ Glo,
    const u16* __restrict__ Thi, const u16* __restrict__ Tlo,
    const float2* __restrict__ L64,
    float* __restrict__ y)
{
    __shared__ __align__(16) char smem[81920];
    const int U_HI = 0, U_LO = 8192, XHo = 16384, XLo = 32768, VY = 49152;

    const int bid = blockIdx.x;
    const int b = bid >> 8;
    const int h = ((bid >> 3) & 31) * 8 + (bid & 7);   // same-h blocks share an XCD
    const int tid = threadIdx.x;
    const int w = tid >> 6, l = tid & 63;
    const int l15 = l & 15, lhi = l >> 4;

    // ---- stage u -> bf16 hi/lo (swizzled) ----
    const float* urow = u + ((size_t)b * HDIM + h) * LDIM;
    const float4* up4 = (const float4*)urow;
    #pragma unroll
    for (int j = 0; j < 4; ++j) {
        float4 f = up4[256 * w + 64 * j + l];
        int e0 = 1024 * w + 256 * j + 4 * l;
        float fv[4] = {f.x, f.y, f.z, f.w};
        ushort4x hv, lv;
        #pragma unroll
        for (int q = 0; q < 4; ++q) {
            u16 hq = f2bf(fv[q]);
            hv[q] = hq;
            lv[q] = f2bf(fv[q] - bf2f(hq));
        }
        int c = e0 >> 6;
        int bh = 2 * e0;
        int sw = (c & 7) << 4;
        *(ushort4x*)(smem + U_HI + (bh ^ sw)) = hv;
        *(ushort4x*)(smem + U_LO + (bh ^ sw)) = lv;
    }
    __syncthreads();

    // ---- B-fragments of U for this wave's 16 columns ----
    const int cB = 16 * w + l15;
    const int swB = (cB & 7) << 4;
    short8x ubh[2], ubl[2];
    #pragma unroll
    for (int ks = 0; ks < 2; ++ks) {
        int bh = 128 * cB + 64 * ks + 16 * lhi;
        ubh[ks] = *(const short8x*)(smem + U_HI + (bh ^ swB));
        ubl[ks] = *(const short8x*)(smem + U_LO + (bh ^ swB));
    }

    // ---- V = P_stack x U ----
    const u16* Ph = Phi + (size_t)h * 8192;
    const u16* Pl = Plo + (size_t)h * 8192;
    #pragma unroll
    for (int mi = 0; mi < 8; ++mi) {
        f32x4 acc = {0.0f, 0.0f, 0.0f, 0.0f};
        #pragma unroll
        for (int ks = 0; ks < 2; ++ks) {
            int off = (16 * mi + l15) * 64 + 32 * ks + 8 * lhi;
            short8x ah = *(const short8x*)(Ph + off);
            short8x al = *(const short8x*)(Pl + off);
            acc = __builtin_amdgcn_mfma_f32_16x16x32_bf16(ah, ubh[ks], acc, 0, 0, 0);
            acc = __builtin_amdgcn_mfma_f32_16x16x32_bf16(ah, ubl[ks], acc, 0, 0, 0);
            acc = __builtin_amdgcn_mfma_f32_16x16x32_bf16(al, ubh[ks], acc, 0, 0, 0);
        }
        #pragma unroll
        for (int r = 0; r < 4; ++r) {
            int row = 16 * mi + 4 * lhi + r;          // V_lds[c][row], row-stride 4B
            int byte = 512 * cB + 4 * row;
            *(float*)(smem + VY + (byte ^ swB)) = acc[r];
        }
    }
    __syncthreads();

    // ---- serial chunk-state scan (wave 0, lane = n) ----
    if (w == 0) {
        float2 lt = L64[h * 64 + l];
        float xr = 0.0f, xi = 0.0f;
        for (int c = 0; c < NCH; ++c) {
            int sw = (c & 7) << 4;
            u16 hr = f2bf(xr), hi2 = f2bf(xi);
            *(u16*)(smem + XHo + ((256 * c + 2 * l) ^ sw)) = hr;
            *(u16*)(smem + XHo + ((256 * c + 128 + 2 * l) ^ sw)) = hi2;
            *(u16*)(smem + XLo + ((256 * c + 2 * l) ^ sw)) = f2bf(xr - bf2f(hr));
            *(u16*)(smem + XLo + ((256 * c + 128 + 2 * l) ^ sw)) = f2bf(xi - bf2f(hi2));
            float vre = *(const float*)(smem + VY + ((512 * c + 4 * l) ^ sw));
            float vim = *(const float*)(smem + VY + ((512 * c + 256 + 4 * l) ^ sw));
            float nr = fmaf(lt.x, xr, fmaf(-lt.y, xi, vre));
            float ni = fmaf(lt.x, xi, fmaf( lt.y, xr, vim));
            xr = nr; xi = ni;
        }
    }
    __syncthreads();

    // ---- Y = G_stack x X + T x U  (accumulated per output tile) ----
    short8x xbh[4], xbl[4];
    #pragma unroll
    for (int ks = 0; ks < 4; ++ks) {
        int bh = 256 * cB + 64 * ks + 16 * lhi;
        xbh[ks] = *(const short8x*)(smem + XHo + (bh ^ swB));
        xbl[ks] = *(const short8x*)(smem + XLo + (bh ^ swB));
    }
    const u16* Gh_ = Ghi + (size_t)h * 8192;
    const u16* Gl_ = Glo + (size_t)h * 8192;
    const u16* Th_ = Thi + (size_t)h * 4096;
    const u16* Tl_ = Tlo + (size_t)h * 4096;
    #pragma unroll
    for (int mi = 0; mi < 4; ++mi) {
        f32x4 acc = {0.0f, 0.0f, 0.0f, 0.0f};
        #pragma unroll
        for (int ks = 0; ks < 4; ++ks) {
            int off = (16 * mi + l15) * 128 + 32 * ks + 8 * lhi;
            short8x ah = *(const short8x*)(Gh_ + off);
            short8x al = *(const short8x*)(Gl_ + off);
            acc = __builtin_amdgcn_mfma_f32_16x16x32_bf16(ah, xbh[ks], acc, 0, 0, 0);
            acc = __builtin_amdgcn_mfma_f32_16x16x32_bf16(ah, xbl[ks], acc, 0, 0, 0);
            acc = __builtin_amdgcn_mfma_f32_16x16x32_bf16(al, xbh[ks], acc, 0, 0, 0);
        }
        #pragma unroll
        for (int ks = 0; ks < 2; ++ks) {
            int off = (16 * mi + l15) * 64 + 32 * ks + 8 * lhi;
            short8x ah = *(const short8x*)(Th_ + off);
            short8x al = *(const short8x*)(Tl_ + off);
            acc = __builtin_amdgcn_mfma_f32_16x16x32_bf16(ah, ubh[ks], acc, 0, 0, 0);
            acc = __builtin_amdgcn_mfma_f32_16x16x32_bf16(ah, ubl[ks], acc, 0, 0, 0);
            acc = __builtin_amdgcn_mfma_f32_16x16x32_bf16(al, ubh[ks], acc, 0, 0, 0);
        }
        #pragma unroll
        for (int r = 0; r < 4; ++r) {
            int t = 16 * mi + 4 * lhi + r;            // Y_lds[c][t], aliases V (dead)
            int byte = 256 * cB + 4 * t;
            *(float*)(smem + VY + (byte ^ swB)) = acc[r];
        }
    }
    __syncthreads();

    // ---- epilogue: y = tanh(Y + D*u) ----
    const float Dh = Dg[h];
    float* yrow = y + ((size_t)b * HDIM + h) * LDIM;
    #pragma unroll
    for (int k = 0; k < 16; ++k) {
        int g = k * 256 + tid;
        int c = g >> 6, t = g & 63;
        float yv = *(const float*)(smem + VY + ((256 * c + 4 * t) ^ ((c & 7) << 4)));
        float uv = urow[g];
        yrow[g] = tanh_fast(fmaf(Dh, uv, yv));
    }
}

// ---------------------------------------------------------------------------
// W transpose: [512][256] -> [256][512]
// ---------------------------------------------------------------------------
__global__ __launch_bounds__(256) void transpose_w(
    const float* __restrict__ W, float* __restrict__ Wt)
{
    const int idx = blockIdx.x * 256 + threadIdx.x;
    const int o  = idx & 511;
    const int hp = idx >> 9;
    Wt[hp * 512 + o] = W[o * 256 + hp];
}

// ---------------------------------------------------------------------------
// Mix + GLU, in-place on d_out per (b, l-tile) slice.
// ---------------------------------------------------------------------------
__global__ __launch_bounds__(256) void mix_kernel(
    float* __restrict__ y,                 // aliases out
    const float* __restrict__ Wt,          // [256][512]
    const float* __restrict__ bm,          // [512]
    float* __restrict__ out)
{
    const int h  = threadIdx.x;
    const int b  = blockIdx.y;
    const int l0 = blockIdx.x * 32;

    const float* ybase = y + ((size_t)b * HDIM) * LDIM + l0;

    float acc_a[32], acc_g[32];
    const float ba = bm[h], bg = bm[h + 256];
    #pragma unroll
    for (int j = 0; j < 32; ++j) { acc_a[j] = ba; acc_g[j] = bg; }

    for (int hp = 0; hp < HDIM; ++hp) {
        const float wa = Wt[hp * 512 + h];
        const float wg = Wt[hp * 512 + 256 + h];
        const float* yr = ybase + (size_t)hp * LDIM;
        #pragma unroll
        for (int j = 0; j < 32; ++j) {
            const float yv = yr[j];
            acc_a[j] = fmaf(wa, yv, acc_a[j]);
            acc_g[j] = fmaf(wg, yv, acc_g[j]);
        }
    }

    __syncthreads();

    float* op = out + ((size_t)b * HDIM + h) * LDIM + l0;
    #pragma unroll
    for (int j = 0; j < 32; ++j) {
        const float g = acc_g[j];
        const float s = rcp_fast(1.0f + __expf(-g));
        op[j] = acc_a[j] * s;
    }
}

// ---------------------------------------------------------------------------
extern "C" void kernel_launch(void* const* d_in, const int* in_sizes, int n_in,
                              void* d_out, int out_size, void* d_ws, size_t ws_size,
                              hipStream_t stream)
{
    const float* u    = (const float*)d_in[0];
    const float* lre  = (const float*)d_in[1];
    const float* lim  = (const float*)d_in[2];
    const float* cbre = (const float*)d_in[3];
    const float* cbim = (const float*)d_in[4];
    const float* Dg   = (const float*)d_in[5];
    const float* W    = (const float*)d_in[6];
    const float* bm   = (const float*)d_in[7];
    float* out = (float*)d_out;

    char* ws = (char*)d_ws;
    size_t o = 0;
    float* Wt  = (float*)(ws + o); o += (size_t)1 << 19;   // 512 KB
    u16* Phi = (u16*)(ws + o); o += (size_t)1 << 22;       // 4 MB each
    u16* Plo = (u16*)(ws + o); o += (size_t)1 << 22;
    u16* Ghi = (u16*)(ws + o); o += (size_t)1 << 22;
    u16* Glo = (u16*)(ws + o); o += (size_t)1 << 22;
    u16* Thi = (u16*)(ws + o); o += (size_t)1 << 21;       // 2 MB each
    u16* Tlo = (u16*)(ws + o); o += (size_t)1 << 21;
    float2* L64 = (float2*)(ws + o);                       // 128 KB

    tables2_kernel<<<HDIM, 64, 0, stream>>>(lre, lim, cbre, cbim,
                                            Phi, Plo, Ghi, Glo, Thi, Tlo, L64);
    transpose_w<<<512, 256, 0, stream>>>(W, Wt);
    scan3_kernel<<<BDIM * HDIM, 256, 0, stream>>>(u, Dg, Phi, Plo, Ghi, Glo,
                                                  Thi, Tlo, L64, out);
    dim3 grid(LDIM / 32, BDIM);
    mix_kernel<<<grid, 256, 0, stream>>>(out, Wt, bm, out);
}

// Round 4
// 205.017 us; speedup vs baseline: 3.5486x; 1.1765x over previous
//
#include <hip/hip_runtime.h>
#include <hip/hip_bf16.h>
#include <cmath>

#define BDIM 8
#define HDIM 256
#define LDIM 4096
#define NDIM 64
#define TCH  64
#define NCH  64

typedef unsigned short u16;
typedef unsigned int   u32;
typedef __attribute__((ext_vector_type(8))) short short8x;
typedef __attribute__((ext_vector_type(4))) float f32x4;
typedef __attribute__((ext_vector_type(4))) unsigned short ushort4x;

__device__ __forceinline__ float rcp_fast(float x) { return __builtin_amdgcn_rcpf(x); }
__device__ __forceinline__ float tanh_fast(float x) {
    float e = __expf(2.0f * x);
    return 1.0f - 2.0f * rcp_fast(e + 1.0f);
}
__device__ __forceinline__ u16 f2bf(float f) {
    unsigned int u = __float_as_uint(f);
    u = u + 0x7fffu + ((u >> 16) & 1u);
    return (u16)(u >> 16);
}
__device__ __forceinline__ float bf2f(u16 s) {
    return __uint_as_float(((unsigned int)s) << 16);
}

// ---------------------------------------------------------------------------
// Tables (one wave per h):
//  P_stack [128 rows(n' = n re / n+64 im)][64 s]  = Lam_n^{63-s}      (bf16 hi/lo)
//  G_stack [64 t][128 n']: [n]=2Re(CB Lam^{t+1}), [n+64]=-2Im(...)    (bf16 hi/lo)
//  T       [64 t][64 s] = K[t-s] (t>=s), K[d]=2Re(sum CB Lam^d)       (bf16 hi/lo)
//  L64     [n] = Lam_n^64                                             (f32)
// ---------------------------------------------------------------------------
__global__ __launch_bounds__(64) void tables2_kernel(
    const float* __restrict__ lre_g, const float* __restrict__ lim_g,
    const float* __restrict__ cbre_g, const float* __restrict__ cbim_g,
    u16* __restrict__ Phi, u16* __restrict__ Plo,
    u16* __restrict__ Ghi, u16* __restrict__ Glo,
    u16* __restrict__ Thi, u16* __restrict__ Tlo,
    float2* __restrict__ L64)
{
    __shared__ float Ksh[64];
    const int h = blockIdx.x, n = threadIdx.x;
    const float lr = lre_g[h * 64 + n], li = lim_g[h * 64 + n];
    const float cr = 2.0f * cbre_g[h * 64 + n];
    const float ci = 2.0f * cbim_g[h * 64 + n];

    u16* Ph = Phi + (size_t)h * 8192; u16* Pl = Plo + (size_t)h * 8192;
    u16* Gh = Ghi + (size_t)h * 8192; u16* Gl = Glo + (size_t)h * 8192;
    u16* Th = Thi + (size_t)h * 4096; u16* Tl = Tlo + (size_t)h * 4096;

    float qr = 1.0f, qi = 0.0f;                      // Lam^t
    for (int t = 0; t < 64; ++t) {
        float kp = cr * qr - ci * qi;                // 2Re(CB Lam^t)
        #pragma unroll
        for (int m = 32; m > 0; m >>= 1) kp += __shfl_xor(kp, m);
        if (n == 0) Ksh[t] = kp;

        int sre = n * 64 + (63 - t), sim = (n + 64) * 64 + (63 - t);
        u16 hre = f2bf(qr); Ph[sre] = hre; Pl[sre] = f2bf(qr - bf2f(hre));
        u16 him = f2bf(qi); Ph[sim] = him; Pl[sim] = f2bf(qi - bf2f(him));

        float nqr = qr * lr - qi * li;               // Lam^{t+1}
        float nqi = qr * li + qi * lr;
        qr = nqr; qi = nqi;

        float gre = cr * qr - ci * qi;               // 2Re(CB Lam^{t+1})
        float gim = cr * qi + ci * qr;               // 2Im(...)
        int o1 = t * 128 + n, o2 = o1 + 64;
        u16 g1 = f2bf(gre);  Gh[o1] = g1; Gl[o1] = f2bf(gre - bf2f(g1));
        float ngim = -gim;
        u16 g2 = f2bf(ngim); Gh[o2] = g2; Gl[o2] = f2bf(ngim - bf2f(g2));
    }
    L64[h * 64 + n] = make_float2(qr, qi);           // Lam^64
    __syncthreads();
    for (int r = 0; r < 64; ++r) {
        float val = (n <= r) ? Ksh[r - n] : 0.0f;
        u16 hv = f2bf(val);
        Th[r * 64 + n] = hv; Tl[r * 64 + n] = f2bf(val - bf2f(hv));
    }
}

// ---------------------------------------------------------------------------
// MFMA chunked scan: one block per (b,h), 4 waves, wave w owns cols 16w..16w+15.
// ---------------------------------------------------------------------------
__global__ __launch_bounds__(256) void scan3_kernel(
    const float* __restrict__ u,
    const float* __restrict__ Dg,
    const u16* __restrict__ Phi, const u16* __restrict__ Plo,
    const u16* __restrict__ Ghi, const u16* __restrict__ Glo,
    const u16* __restrict__ Thi, const u16* __restrict__ Tlo,
    const float2* __restrict__ L64,
    float* __restrict__ y)
{
    __shared__ __align__(16) char smem[81920];
    const int U_HI = 0, U_LO = 8192, XHo = 16384, XLo = 32768, VY = 49152;

    const int bid = blockIdx.x;
    const int b = bid >> 8;
    const int h = ((bid >> 3) & 31) * 8 + (bid & 7);
    const int tid = threadIdx.x;
    const int w = tid >> 6, l = tid & 63;
    const int l15 = l & 15, lhi = l >> 4;

    // ---- stage u -> bf16 hi/lo (swizzled) ----
    const float* urow = u + ((size_t)b * HDIM + h) * LDIM;
    const float4* up4 = (const float4*)urow;
    #pragma unroll
    for (int j = 0; j < 4; ++j) {
        float4 f = up4[256 * w + 64 * j + l];
        int e0 = 1024 * w + 256 * j + 4 * l;
        float fv[4] = {f.x, f.y, f.z, f.w};
        ushort4x hv, lv;
        #pragma unroll
        for (int q = 0; q < 4; ++q) {
            u16 hq = f2bf(fv[q]);
            hv[q] = hq;
            lv[q] = f2bf(fv[q] - bf2f(hq));
        }
        int c = e0 >> 6;
        int bh = 2 * e0;
        int sw = (c & 7) << 4;
        *(ushort4x*)(smem + U_HI + (bh ^ sw)) = hv;
        *(ushort4x*)(smem + U_LO + (bh ^ sw)) = lv;
    }
    __syncthreads();

    // ---- B-fragments of U for this wave's 16 columns ----
    const int cB = 16 * w + l15;
    const int swB = (cB & 7) << 4;
    short8x ubh[2], ubl[2];
    #pragma unroll
    for (int ks = 0; ks < 2; ++ks) {
        int bh = 128 * cB + 64 * ks + 16 * lhi;
        ubh[ks] = *(const short8x*)(smem + U_HI + (bh ^ swB));
        ubl[ks] = *(const short8x*)(smem + U_LO + (bh ^ swB));
    }

    // ---- V = P_stack x U ----
    const u16* Ph = Phi + (size_t)h * 8192;
    const u16* Pl = Plo + (size_t)h * 8192;
    #pragma unroll
    for (int mi = 0; mi < 8; ++mi) {
        f32x4 acc = {0.0f, 0.0f, 0.0f, 0.0f};
        #pragma unroll
        for (int ks = 0; ks < 2; ++ks) {
            int off = (16 * mi + l15) * 64 + 32 * ks + 8 * lhi;
            short8x ah = *(const short8x*)(Ph + off);
            short8x al = *(const short8x*)(Pl + off);
            acc = __builtin_amdgcn_mfma_f32_16x16x32_bf16(ah, ubh[ks], acc, 0, 0, 0);
            acc = __builtin_amdgcn_mfma_f32_16x16x32_bf16(ah, ubl[ks], acc, 0, 0, 0);
            acc = __builtin_amdgcn_mfma_f32_16x16x32_bf16(al, ubh[ks], acc, 0, 0, 0);
        }
        #pragma unroll
        for (int r = 0; r < 4; ++r) {
            int row = 16 * mi + 4 * lhi + r;
            int byte = 512 * cB + 4 * row;
            *(float*)(smem + VY + (byte ^ swB)) = acc[r];
        }
    }
    __syncthreads();

    // ---- serial chunk-state scan (wave 0, lane = n) ----
    if (w == 0) {
        float2 lt = L64[h * 64 + l];
        float xr = 0.0f, xi = 0.0f;
        for (int c = 0; c < NCH; ++c) {
            int sw = (c & 7) << 4;
            u16 hr = f2bf(xr), hi2 = f2bf(xi);
            *(u16*)(smem + XHo + ((256 * c + 2 * l) ^ sw)) = hr;
            *(u16*)(smem + XHo + ((256 * c + 128 + 2 * l) ^ sw)) = hi2;
            *(u16*)(smem + XLo + ((256 * c + 2 * l) ^ sw)) = f2bf(xr - bf2f(hr));
            *(u16*)(smem + XLo + ((256 * c + 128 + 2 * l) ^ sw)) = f2bf(xi - bf2f(hi2));
            float vre = *(const float*)(smem + VY + ((512 * c + 4 * l) ^ sw));
            float vim = *(const float*)(smem + VY + ((512 * c + 256 + 4 * l) ^ sw));
            float nr = fmaf(lt.x, xr, fmaf(-lt.y, xi, vre));
            float ni = fmaf(lt.x, xi, fmaf( lt.y, xr, vim));
            xr = nr; xi = ni;
        }
    }
    __syncthreads();

    // ---- Y = G_stack x X + T x U ----
    short8x xbh[4], xbl[4];
    #pragma unroll
    for (int ks = 0; ks < 4; ++ks) {
        int bh = 256 * cB + 64 * ks + 16 * lhi;
        xbh[ks] = *(const short8x*)(smem + XHo + (bh ^ swB));
        xbl[ks] = *(const short8x*)(smem + XLo + (bh ^ swB));
    }
    const u16* Gh_ = Ghi + (size_t)h * 8192;
    const u16* Gl_ = Glo + (size_t)h * 8192;
    const u16* Th_ = Thi + (size_t)h * 4096;
    const u16* Tl_ = Tlo + (size_t)h * 4096;
    #pragma unroll
    for (int mi = 0; mi < 4; ++mi) {
        f32x4 acc = {0.0f, 0.0f, 0.0f, 0.0f};
        #pragma unroll
        for (int ks = 0; ks < 4; ++ks) {
            int off = (16 * mi + l15) * 128 + 32 * ks + 8 * lhi;
            short8x ah = *(const short8x*)(Gh_ + off);
            short8x al = *(const short8x*)(Gl_ + off);
            acc = __builtin_amdgcn_mfma_f32_16x16x32_bf16(ah, xbh[ks], acc, 0, 0, 0);
            acc = __builtin_amdgcn_mfma_f32_16x16x32_bf16(ah, xbl[ks], acc, 0, 0, 0);
            acc = __builtin_amdgcn_mfma_f32_16x16x32_bf16(al, xbh[ks], acc, 0, 0, 0);
        }
        #pragma unroll
        for (int ks = 0; ks < 2; ++ks) {
            int off = (16 * mi + l15) * 64 + 32 * ks + 8 * lhi;
            short8x ah = *(const short8x*)(Th_ + off);
            short8x al = *(const short8x*)(Tl_ + off);
            acc = __builtin_amdgcn_mfma_f32_16x16x32_bf16(ah, ubh[ks], acc, 0, 0, 0);
            acc = __builtin_amdgcn_mfma_f32_16x16x32_bf16(ah, ubl[ks], acc, 0, 0, 0);
            acc = __builtin_amdgcn_mfma_f32_16x16x32_bf16(al, ubh[ks], acc, 0, 0, 0);
        }
        #pragma unroll
        for (int r = 0; r < 4; ++r) {
            int t = 16 * mi + 4 * lhi + r;
            int byte = 256 * cB + 4 * t;
            *(float*)(smem + VY + (byte ^ swB)) = acc[r];
        }
    }
    __syncthreads();

    // ---- epilogue: y = tanh(Y + D*u) ----
    const float Dh = Dg[h];
    float* yrow = y + ((size_t)b * HDIM + h) * LDIM;
    #pragma unroll
    for (int k = 0; k < 16; ++k) {
        int g = k * 256 + tid;
        int c = g >> 6, t = g & 63;
        float yv = *(const float*)(smem + VY + ((256 * c + 4 * t) ^ ((c & 7) << 4)));
        float uv = urow[g];
        yrow[g] = tanh_fast(fmaf(Dh, uv, yv));
    }
}

// ---------------------------------------------------------------------------
// W prep: Wp[r][h], r even -> W[r/2] (a-row), r odd -> W[r/2+256] (g-row);
// exact split into bf16 hi + lo, row-major [512][256] for direct A-fragments.
// ---------------------------------------------------------------------------
__global__ __launch_bounds__(256) void prep_w(
    const float* __restrict__ W, u16* __restrict__ Wphi, u16* __restrict__ Wplo)
{
    const int r = blockIdx.x, hcol = threadIdx.x;
    const int src = (r & 1) ? (r >> 1) + 256 : (r >> 1);
    float v = W[src * 256 + hcol];
    u16 hv = f2bf(v);
    Wphi[r * 256 + hcol] = hv;
    Wplo[r * 256 + hcol] = f2bf(v - bf2f(hv));
}

// ---------------------------------------------------------------------------
// MFMA mix + GLU. Block: BM=512 (all Wp rows) x BN=32 cols, 4 waves (wave w
// owns Wp rows 128w..128w+127). K=256 in 4 steps of 64, Y staged in LDS as
// bf16 [col][k] (transposed during staging, XOR-swizzled). In-place on d_out:
// each block reads exactly the (b, col-slice) it later overwrites.
// ---------------------------------------------------------------------------
__global__ __launch_bounds__(256) void mix2_kernel(
    const float* y,                        // d_out: scan output [B][256][4096]
    const u16* __restrict__ Wphi, const u16* __restrict__ Wplo,
    const float* __restrict__ bm,
    float* out)                            // d_out (aliases y)
{
    __shared__ __align__(16) u16 Ysh[32 * 64];     // 4KB, [col][k] swizzled

    const int tid = threadIdx.x;
    const int w = tid >> 6, l = tid & 63;
    const int l15 = l & 15, lhi = l >> 4;
    const int b = blockIdx.y;
    const int col0 = blockIdx.x * 32;

    const float* Yb = y + ((size_t)b * HDIM) * LDIM;

    // staging map: thread -> k-pair p (rows 2p,2p+1), col group cg (4 cols)
    const int p  = tid >> 3;
    const int cg = tid & 7;

    f32x4 acc[8][2];
    #pragma unroll
    for (int mi = 0; mi < 8; ++mi)
        #pragma unroll
        for (int ct = 0; ct < 2; ++ct)
            acc[mi][ct] = (f32x4){0.0f, 0.0f, 0.0f, 0.0f};

    for (int kb = 0; kb < 4; ++kb) {
        const int k0 = kb * 64;
        // ---- stage Y[k0..k0+63][col0..col0+31] -> bf16 LDS [col][k] ----
        const float* r0 = Yb + (size_t)(k0 + 2 * p) * LDIM + col0 + 4 * cg;
        float4 f0 = *(const float4*)r0;
        float4 f1 = *(const float4*)(r0 + LDIM);
        float f0v[4] = {f0.x, f0.y, f0.z, f0.w};
        float f1v[4] = {f1.x, f1.y, f1.z, f1.w};
        #pragma unroll
        for (int q = 0; q < 4; ++q) {
            int col = 4 * cg + q;
            u32 wv = (u32)f2bf(f0v[q]) | ((u32)f2bf(f1v[q]) << 16);
            int byte = (col * 128 + 4 * p) ^ ((col & 7) << 4);
            *(u32*)((char*)Ysh + byte) = wv;
        }
        __syncthreads();

        // ---- B fragments ----
        short8x yb[2][2];
        #pragma unroll
        for (int ct = 0; ct < 2; ++ct)
            #pragma unroll
            for (int ks = 0; ks < 2; ++ks) {
                int col = 16 * ct + l15;
                int byte = (col * 128 + 64 * ks + 16 * lhi) ^ ((col & 7) << 4);
                yb[ct][ks] = *(const short8x*)((char*)Ysh + byte);
            }

        // ---- MFMA: rows 128w + 16mi + frag ----
        const u16* WhB = Wphi + (size_t)(128 * w) * 256 + k0;
        const u16* WlB = Wplo + (size_t)(128 * w) * 256 + k0;
        #pragma unroll
        for (int mi = 0; mi < 8; ++mi) {
            #pragma unroll
            for (int ks = 0; ks < 2; ++ks) {
                size_t off = (size_t)(16 * mi + l15) * 256 + 32 * ks + 8 * lhi;
                short8x ah = *(const short8x*)(WhB + off);
                short8x al = *(const short8x*)(WlB + off);
                #pragma unroll
                for (int ct = 0; ct < 2; ++ct) {
                    acc[mi][ct] = __builtin_amdgcn_mfma_f32_16x16x32_bf16(ah, yb[ct][ks], acc[mi][ct], 0, 0, 0);
                    acc[mi][ct] = __builtin_amdgcn_mfma_f32_16x16x32_bf16(al, yb[ct][ks], acc[mi][ct], 0, 0, 0);
                }
            }
        }
        __syncthreads();
    }

    // ---- epilogue: bias + GLU + store ----
    float* ob = out + ((size_t)b * HDIM) * LDIM;
    #pragma unroll
    for (int mi = 0; mi < 8; ++mi) {
        int r0 = 128 * w + 16 * mi + 4 * lhi;   // even
        int h1 = r0 >> 1;                        // rows r0,r0+1 -> h1; r0+2,r0+3 -> h1+1
        float ba1 = bm[h1],     bg1 = bm[h1 + 256];
        float ba2 = bm[h1 + 1], bg2 = bm[h1 + 1 + 256];
        #pragma unroll
        for (int ct = 0; ct < 2; ++ct) {
            f32x4 a = acc[mi][ct];
            int col = col0 + 16 * ct + l15;
            float A1 = a[0] + ba1, G1 = a[1] + bg1;
            float A2 = a[2] + ba2, G2 = a[3] + bg2;
            ob[(size_t)h1 * LDIM + col]       = A1 * rcp_fast(1.0f + __expf(-G1));
            ob[(size_t)(h1 + 1) * LDIM + col] = A2 * rcp_fast(1.0f + __expf(-G2));
        }
    }
}

// ---------------------------------------------------------------------------
extern "C" void kernel_launch(void* const* d_in, const int* in_sizes, int n_in,
                              void* d_out, int out_size, void* d_ws, size_t ws_size,
                              hipStream_t stream)
{
    const float* u    = (const float*)d_in[0];
    const float* lre  = (const float*)d_in[1];
    const float* lim  = (const float*)d_in[2];
    const float* cbre = (const float*)d_in[3];
    const float* cbim = (const float*)d_in[4];
    const float* Dg   = (const float*)d_in[5];
    const float* W    = (const float*)d_in[6];
    const float* bm   = (const float*)d_in[7];
    float* out = (float*)d_out;

    char* ws = (char*)d_ws;
    size_t o = 0;
    u16* Wphi = (u16*)(ws + o); o += (size_t)1 << 18;      // 256 KB
    u16* Wplo = (u16*)(ws + o); o += (size_t)1 << 18;      // 256 KB
    u16* Phi = (u16*)(ws + o); o += (size_t)1 << 22;       // 4 MB each
    u16* Plo = (u16*)(ws + o); o += (size_t)1 << 22;
    u16* Ghi = (u16*)(ws + o); o += (size_t)1 << 22;
    u16* Glo = (u16*)(ws + o); o += (size_t)1 << 22;
    u16* Thi = (u16*)(ws + o); o += (size_t)1 << 21;       // 2 MB each
    u16* Tlo = (u16*)(ws + o); o += (size_t)1 << 21;
    float2* L64 = (float2*)(ws + o);                       // 128 KB

    tables2_kernel<<<HDIM, 64, 0, stream>>>(lre, lim, cbre, cbim,
                                            Phi, Plo, Ghi, Glo, Thi, Tlo, L64);
    prep_w<<<512, 256, 0, stream>>>(W, Wphi, Wplo);
    scan3_kernel<<<BDIM * HDIM, 256, 0, stream>>>(u, Dg, Phi, Plo, Ghi, Glo,
                                                  Thi, Tlo, L64, out);
    dim3 grid(LDIM / 32, BDIM);
    mix2_kernel<<<grid, 256, 0, stream>>>(out, Wphi, Wplo, bm, out);
}

// Round 5
// 191.898 us; speedup vs baseline: 3.7912x; 1.0684x over previous
//
#include <hip/hip_runtime.h>
#include <hip/hip_bf16.h>
#include <cmath>

#define BDIM 8
#define HDIM 256
#define LDIM 4096
#define NDIM 64
#define TCH  64
#define NCH  64

typedef unsigned short u16;
typedef unsigned int   u32;
typedef __attribute__((ext_vector_type(8))) short short8x;
typedef __attribute__((ext_vector_type(4))) float f32x4;

__device__ __forceinline__ float rcp_fast(float x) { return __builtin_amdgcn_rcpf(x); }
__device__ __forceinline__ float tanh_fast(float x) {
    float e = __expf(2.0f * x);
    return 1.0f - 2.0f * rcp_fast(e + 1.0f);
}
__device__ __forceinline__ u16 f2bf(float f) {
    unsigned int u = __float_as_uint(f);
    u = u + 0x7fffu + ((u >> 16) & 1u);
    return (u16)(u >> 16);
}
__device__ __forceinline__ float bf2f(u16 s) {
    return __uint_as_float(((unsigned int)s) << 16);
}

// ---------------------------------------------------------------------------
// Tables (one wave per h). INTERLEAVED n'' = 2n (re) / 2n+1 (im):
//  P_stack [128 n''][64 s] : [2n]=Re(Lam^{63-s}), [2n+1]=Im            (bf16 hi/lo)
//  G_stack [64 t][128 n''] : [2n]=2Re(CB Lam^{t+1}), [2n+1]=-2Im(...)  (bf16 hi/lo)
//  T       [64 t][64 s]    : K[t-s] (t>=s), K[d]=2Re(sum CB Lam^d)     (bf16 hi/lo)
//  L64     [n] = Lam_n^64                                              (f32)
// ---------------------------------------------------------------------------
__global__ __launch_bounds__(64) void tables2_kernel(
    const float* __restrict__ lre_g, const float* __restrict__ lim_g,
    const float* __restrict__ cbre_g, const float* __restrict__ cbim_g,
    u16* __restrict__ Phi, u16* __restrict__ Plo,
    u16* __restrict__ Ghi, u16* __restrict__ Glo,
    u16* __restrict__ Thi, u16* __restrict__ Tlo,
    float2* __restrict__ L64)
{
    __shared__ float Ksh[64];
    const int h = blockIdx.x, n = threadIdx.x;
    const float lr = lre_g[h * 64 + n], li = lim_g[h * 64 + n];
    const float cr = 2.0f * cbre_g[h * 64 + n];
    const float ci = 2.0f * cbim_g[h * 64 + n];

    u16* Ph = Phi + (size_t)h * 8192; u16* Pl = Plo + (size_t)h * 8192;
    u16* Gh = Ghi + (size_t)h * 8192; u16* Gl = Glo + (size_t)h * 8192;
    u16* Th = Thi + (size_t)h * 4096; u16* Tl = Tlo + (size_t)h * 4096;

    float qr = 1.0f, qi = 0.0f;                      // Lam^t
    for (int t = 0; t < 64; ++t) {
        float kp = cr * qr - ci * qi;                // 2Re(CB Lam^t)
        #pragma unroll
        for (int m = 32; m > 0; m >>= 1) kp += __shfl_xor(kp, m);
        if (n == 0) Ksh[t] = kp;

        int sre = (2 * n) * 64 + (63 - t), sim = (2 * n + 1) * 64 + (63 - t);
        u16 hre = f2bf(qr); Ph[sre] = hre; Pl[sre] = f2bf(qr - bf2f(hre));
        u16 him = f2bf(qi); Ph[sim] = him; Pl[sim] = f2bf(qi - bf2f(him));

        float nqr = qr * lr - qi * li;               // Lam^{t+1}
        float nqi = qr * li + qi * lr;
        qr = nqr; qi = nqi;

        float gre = cr * qr - ci * qi;               // 2Re(CB Lam^{t+1})
        float gim = cr * qi + ci * qr;               // 2Im(...)
        int o1 = t * 128 + 2 * n, o2 = o1 + 1;
        u16 g1 = f2bf(gre);  Gh[o1] = g1; Gl[o1] = f2bf(gre - bf2f(g1));
        float ngim = -gim;
        u16 g2 = f2bf(ngim); Gh[o2] = g2; Gl[o2] = f2bf(ngim - bf2f(g2));
    }
    L64[h * 64 + n] = make_float2(qr, qi);           // Lam^64
    __syncthreads();
    for (int r = 0; r < 64; ++r) {
        float val = (n <= r) ? Ksh[r - n] : 0.0f;
        u16 hv = f2bf(val);
        Th[r * 64 + n] = hv; Tl[r * 64 + n] = f2bf(val - bf2f(hv));
    }
}

// ---------------------------------------------------------------------------
// scan4: one block per (b,h), 4 waves, wave w owns chunks/cols 16w..16w+15.
// LDS: single aliased buffer, 65 rows x 512 B = 33,280 B -> 4 blocks/CU.
//   V[c] (f32[128], interleaved re/im) at row c+1
//   X[c] (bf16 hi[128] | lo[128])      at row c   (overwrites V[c-1])
//   Y[c] (f32[64])                     at row c, bytes 0..255 (over X hi)
// U B-fragments loaded directly from global (no LDS staging). 3 barriers.
// ---------------------------------------------------------------------------
__global__ __launch_bounds__(256, 4) void scan4_kernel(
    const float* __restrict__ u,
    const float* __restrict__ Dg,
    const u16* __restrict__ Phi, const u16* __restrict__ Plo,
    const u16* __restrict__ Ghi, const u16* __restrict__ Glo,
    const u16* __restrict__ Thi, const u16* __restrict__ Tlo,
    const float2* __restrict__ L64,
    float* __restrict__ y)
{
    __shared__ __align__(16) char smem[65 * 512];

    const int bid = blockIdx.x;
    const int b = bid >> 8;
    const int h = ((bid >> 3) & 31) * 8 + (bid & 7);   // same-h blocks share an XCD
    const int tid = threadIdx.x;
    const int w = tid >> 6, l = tid & 63;
    const int l15 = l & 15, lhi = l >> 4;
    const int cB = 16 * w + l15;                       // this lane's column/chunk

    const float* urow = u + ((size_t)b * HDIM + h) * LDIM;

    // ---- U B-fragments direct from global: u[64cB + 32ks + 8lhi + 0..7] ----
    short8x ubh[2], ubl[2];
    #pragma unroll
    for (int ks = 0; ks < 2; ++ks) {
        const float* src = urow + 64 * cB + 32 * ks + 8 * lhi;
        float4 f0 = *(const float4*)src;
        float4 f1 = *(const float4*)(src + 4);
        float fv[8] = {f0.x, f0.y, f0.z, f0.w, f1.x, f1.y, f1.z, f1.w};
        union { short8x v; u16 s[8]; } H, L;
        #pragma unroll
        for (int q = 0; q < 8; ++q) {
            u16 hq = f2bf(fv[q]);
            H.s[q] = hq; L.s[q] = f2bf(fv[q] - bf2f(hq));
        }
        ubh[ks] = H.v; ubl[ks] = L.v;
    }

    // ---- V = P_stack x U -> LDS row cB+1 (b128 C-writes, row-XOR swizzle) ----
    const u16* Ph = Phi + (size_t)h * 8192;
    const u16* Pl = Plo + (size_t)h * 8192;
    {
        const int rV = cB + 1;
        const int swV = (rV & 7) << 4;
        #pragma unroll
        for (int mi = 0; mi < 8; ++mi) {
            f32x4 acc = {0.0f, 0.0f, 0.0f, 0.0f};
            #pragma unroll
            for (int ks = 0; ks < 2; ++ks) {
                int off = (16 * mi + l15) * 64 + 32 * ks + 8 * lhi;
                short8x ah = *(const short8x*)(Ph + off);
                short8x al = *(const short8x*)(Pl + off);
                acc = __builtin_amdgcn_mfma_f32_16x16x32_bf16(ah, ubh[ks], acc, 0, 0, 0);
                acc = __builtin_amdgcn_mfma_f32_16x16x32_bf16(ah, ubl[ks], acc, 0, 0, 0);
                acc = __builtin_amdgcn_mfma_f32_16x16x32_bf16(al, ubh[ks], acc, 0, 0, 0);
            }
            int byte = 512 * rV + 64 * mi + 16 * lhi;
            *(f32x4*)(smem + (byte ^ swV)) = acc;
        }
    }
    __syncthreads();

    // ---- serial chunk-state scan (wave 0, lane = n), V prefetched ----
    if (w == 0) {
        float2 lt = L64[h * 64 + l];
        float xr = 0.0f, xi = 0.0f;
        float2 v = *(const float2*)(smem + ((512 * 1 + 8 * l) ^ (1 << 4)));
        for (int c = 0; c < NCH; ++c) {
            int rn = (c < 62) ? c + 2 : 64;          // next V row (c=63: dummy re-read)
            float2 vn = *(const float2*)(smem + ((512 * rn + 8 * l) ^ ((rn & 7) << 4)));
            int sw = (c & 7) << 4;
            u16 hr = f2bf(xr); u16 lr_ = f2bf(xr - bf2f(hr));
            u16 hi_ = f2bf(xi); u16 li_ = f2bf(xi - bf2f(hi_));
            *(u32*)(smem + ((512 * c + 4 * l) ^ sw))       = (u32)hr  | ((u32)hi_ << 16);
            *(u32*)(smem + ((512 * c + 256 + 4 * l) ^ sw)) = (u32)lr_ | ((u32)li_ << 16);
            float nr = fmaf(lt.x, xr, fmaf(-lt.y, xi, v.x));
            float ni = fmaf(lt.x, xi, fmaf( lt.y, xr, v.y));
            xr = nr; xi = ni;
            v = vn;
        }
    }
    __syncthreads();

    // ---- Y = G_stack x X + T x U  (X B-frags from own rows; Y over X-hi) ----
    const int swX = (cB & 7) << 4;
    short8x xbh[4], xbl[4];
    #pragma unroll
    for (int ks = 0; ks < 4; ++ks) {
        int byte = 512 * cB + 64 * ks + 16 * lhi;
        xbh[ks] = *(const short8x*)(smem + (byte ^ swX));
        xbl[ks] = *(const short8x*)(smem + ((byte + 256) ^ swX));
    }
    const u16* Gh_ = Ghi + (size_t)h * 8192;
    const u16* Gl_ = Glo + (size_t)h * 8192;
    const u16* Th_ = Thi + (size_t)h * 4096;
    const u16* Tl_ = Tlo + (size_t)h * 4096;
    #pragma unroll
    for (int mi = 0; mi < 4; ++mi) {
        f32x4 acc = {0.0f, 0.0f, 0.0f, 0.0f};
        #pragma unroll
        for (int ks = 0; ks < 4; ++ks) {
            int off = (16 * mi + l15) * 128 + 32 * ks + 8 * lhi;
            short8x ah = *(const short8x*)(Gh_ + off);
            short8x al = *(const short8x*)(Gl_ + off);
            acc = __builtin_amdgcn_mfma_f32_16x16x32_bf16(ah, xbh[ks], acc, 0, 0, 0);
            acc = __builtin_amdgcn_mfma_f32_16x16x32_bf16(ah, xbl[ks], acc, 0, 0, 0);
            acc = __builtin_amdgcn_mfma_f32_16x16x32_bf16(al, xbh[ks], acc, 0, 0, 0);
        }
        #pragma unroll
        for (int ks = 0; ks < 2; ++ks) {
            int off = (16 * mi + l15) * 64 + 32 * ks + 8 * lhi;
            short8x ah = *(const short8x*)(Th_ + off);
            short8x al = *(const short8x*)(Tl_ + off);
            acc = __builtin_amdgcn_mfma_f32_16x16x32_bf16(ah, ubh[ks], acc, 0, 0, 0);
            acc = __builtin_amdgcn_mfma_f32_16x16x32_bf16(ah, ubl[ks], acc, 0, 0, 0);
            acc = __builtin_amdgcn_mfma_f32_16x16x32_bf16(al, ubh[ks], acc, 0, 0, 0);
        }
        int byte = 512 * cB + 64 * mi + 16 * lhi;    // Y[cB][t], bytes 0..255
        *(f32x4*)(smem + (byte ^ swX)) = acc;
    }
    __syncthreads();

    // ---- epilogue: y = tanh(Y + D*u), vectorized x4 ----
    const float Dh = Dg[h];
    float* yrow = y + ((size_t)b * HDIM + h) * LDIM;
    #pragma unroll
    for (int k = 0; k < 4; ++k) {
        int g4 = 1024 * k + 4 * tid;
        int c = g4 >> 6, t0 = g4 & 63;
        f32x4 yv = *(const f32x4*)(smem + ((512 * c + 4 * t0) ^ ((c & 7) << 4)));
        float4 uv = *(const float4*)(urow + g4);
        float4 o;
        o.x = tanh_fast(fmaf(Dh, uv.x, yv[0]));
        o.y = tanh_fast(fmaf(Dh, uv.y, yv[1]));
        o.z = tanh_fast(fmaf(Dh, uv.z, yv[2]));
        o.w = tanh_fast(fmaf(Dh, uv.w, yv[3]));
        *(float4*)(yrow + g4) = o;
    }
}

// ---------------------------------------------------------------------------
// W prep: Wp[r][h], r even -> W[r/2] (a-row), r odd -> W[r/2+256] (g-row);
// exact split into bf16 hi + lo, row-major [512][256] for direct A-fragments.
// ---------------------------------------------------------------------------
__global__ __launch_bounds__(256) void prep_w(
    const float* __restrict__ W, u16* __restrict__ Wphi, u16* __restrict__ Wplo)
{
    const int r = blockIdx.x, hcol = threadIdx.x;
    const int src = (r & 1) ? (r >> 1) + 256 : (r >> 1);
    float v = W[src * 256 + hcol];
    u16 hv = f2bf(v);
    Wphi[r * 256 + hcol] = hv;
    Wplo[r * 256 + hcol] = f2bf(v - bf2f(hv));
}

// ---------------------------------------------------------------------------
// MFMA mix + GLU. Block: BM=512 (all Wp rows) x BN=32 cols, 4 waves (wave w
// owns Wp rows 128w..128w+127). K=256 in 4 steps of 64, Y staged in LDS as
// bf16 [col][k] (transposed during staging, XOR-swizzled). In-place on d_out.
// ---------------------------------------------------------------------------
__global__ __launch_bounds__(256) void mix2_kernel(
    const float* y,                        // d_out: scan output [B][256][4096]
    const u16* __restrict__ Wphi, const u16* __restrict__ Wplo,
    const float* __restrict__ bm,
    float* out)                            // d_out (aliases y)
{
    __shared__ __align__(16) u16 Ysh[32 * 64];     // 4KB, [col][k] swizzled

    const int tid = threadIdx.x;
    const int w = tid >> 6, l = tid & 63;
    const int l15 = l & 15, lhi = l >> 4;
    const int b = blockIdx.y;
    const int col0 = blockIdx.x * 32;

    const float* Yb = y + ((size_t)b * HDIM) * LDIM;

    const int p  = tid >> 3;
    const int cg = tid & 7;

    f32x4 acc[8][2];
    #pragma unroll
    for (int mi = 0; mi < 8; ++mi)
        #pragma unroll
        for (int ct = 0; ct < 2; ++ct)
            acc[mi][ct] = (f32x4){0.0f, 0.0f, 0.0f, 0.0f};

    for (int kb = 0; kb < 4; ++kb) {
        const int k0 = kb * 64;
        const float* r0 = Yb + (size_t)(k0 + 2 * p) * LDIM + col0 + 4 * cg;
        float4 f0 = *(const float4*)r0;
        float4 f1 = *(const float4*)(r0 + LDIM);
        float f0v[4] = {f0.x, f0.y, f0.z, f0.w};
        float f1v[4] = {f1.x, f1.y, f1.z, f1.w};
        #pragma unroll
        for (int q = 0; q < 4; ++q) {
            int col = 4 * cg + q;
            u32 wv = (u32)f2bf(f0v[q]) | ((u32)f2bf(f1v[q]) << 16);
            int byte = (col * 128 + 4 * p) ^ ((col & 7) << 4);
            *(u32*)((char*)Ysh + byte) = wv;
        }
        __syncthreads();

        short8x yb[2][2];
        #pragma unroll
        for (int ct = 0; ct < 2; ++ct)
            #pragma unroll
            for (int ks = 0; ks < 2; ++ks) {
                int col = 16 * ct + l15;
                int byte = (col * 128 + 64 * ks + 16 * lhi) ^ ((col & 7) << 4);
                yb[ct][ks] = *(const short8x*)((char*)Ysh + byte);
            }

        const u16* WhB = Wphi + (size_t)(128 * w) * 256 + k0;
        const u16* WlB = Wplo + (size_t)(128 * w) * 256 + k0;
        #pragma unroll
        for (int mi = 0; mi < 8; ++mi) {
            #pragma unroll
            for (int ks = 0; ks < 2; ++ks) {
                size_t off = (size_t)(16 * mi + l15) * 256 + 32 * ks + 8 * lhi;
                short8x ah = *(const short8x*)(WhB + off);
                short8x al = *(const short8x*)(WlB + off);
                #pragma unroll
                for (int ct = 0; ct < 2; ++ct) {
                    acc[mi][ct] = __builtin_amdgcn_mfma_f32_16x16x32_bf16(ah, yb[ct][ks], acc[mi][ct], 0, 0, 0);
                    acc[mi][ct] = __builtin_amdgcn_mfma_f32_16x16x32_bf16(al, yb[ct][ks], acc[mi][ct], 0, 0, 0);
                }
            }
        }
        __syncthreads();
    }

    float* ob = out + ((size_t)b * HDIM) * LDIM;
    #pragma unroll
    for (int mi = 0; mi < 8; ++mi) {
        int r0 = 128 * w + 16 * mi + 4 * lhi;
        int h1 = r0 >> 1;
        float ba1 = bm[h1],     bg1 = bm[h1 + 256];
        float ba2 = bm[h1 + 1], bg2 = bm[h1 + 1 + 256];
        #pragma unroll
        for (int ct = 0; ct < 2; ++ct) {
            f32x4 a = acc[mi][ct];
            int col = col0 + 16 * ct + l15;
            float A1 = a[0] + ba1, G1 = a[1] + bg1;
            float A2 = a[2] + ba2, G2 = a[3] + bg2;
            ob[(size_t)h1 * LDIM + col]       = A1 * rcp_fast(1.0f + __expf(-G1));
            ob[(size_t)(h1 + 1) * LDIM + col] = A2 * rcp_fast(1.0f + __expf(-G2));
        }
    }
}

// ---------------------------------------------------------------------------
extern "C" void kernel_launch(void* const* d_in, const int* in_sizes, int n_in,
                              void* d_out, int out_size, void* d_ws, size_t ws_size,
                              hipStream_t stream)
{
    const float* u    = (const float*)d_in[0];
    const float* lre  = (const float*)d_in[1];
    const float* lim  = (const float*)d_in[2];
    const float* cbre = (const float*)d_in[3];
    const float* cbim = (const float*)d_in[4];
    const float* Dg   = (const float*)d_in[5];
    const float* W    = (const float*)d_in[6];
    const float* bm   = (const float*)d_in[7];
    float* out = (float*)d_out;

    char* ws = (char*)d_ws;
    size_t o = 0;
    u16* Wphi = (u16*)(ws + o); o += (size_t)1 << 18;      // 256 KB
    u16* Wplo = (u16*)(ws + o); o += (size_t)1 << 18;      // 256 KB
    u16* Phi = (u16*)(ws + o); o += (size_t)1 << 22;       // 4 MB each
    u16* Plo = (u16*)(ws + o); o += (size_t)1 << 22;
    u16* Ghi = (u16*)(ws + o); o += (size_t)1 << 22;
    u16* Glo = (u16*)(ws + o); o += (size_t)1 << 22;
    u16* Thi = (u16*)(ws + o); o += (size_t)1 << 21;       // 2 MB each
    u16* Tlo = (u16*)(ws + o); o += (size_t)1 << 21;
    float2* L64 = (float2*)(ws + o);                       // 128 KB

    tables2_kernel<<<HDIM, 64, 0, stream>>>(lre, lim, cbre, cbim,
                                            Phi, Plo, Ghi, Glo, Thi, Tlo, L64);
    prep_w<<<512, 256, 0, stream>>>(W, Wphi, Wplo);
    scan4_kernel<<<BDIM * HDIM, 256, 0, stream>>>(u, Dg, Phi, Plo, Ghi, Glo,
                                                  Thi, Tlo, L64, out);
    dim3 grid(LDIM / 32, BDIM);
    mix2_kernel<<<grid, 256, 0, stream>>>(out, Wphi, Wplo, bm, out);
}

// Round 6
// 135.666 us; speedup vs baseline: 5.3627x; 1.4145x over previous
//
#include <hip/hip_runtime.h>
#include <hip/hip_bf16.h>
#include <cmath>

#define BDIM 8
#define HDIM 256
#define LDIM 4096
#define NDIM 64
#define TCH  64
#define NCH  64

typedef unsigned short u16;
typedef unsigned int   u32;
typedef __attribute__((ext_vector_type(8))) short short8x;
typedef __attribute__((ext_vector_type(4))) float f32x4;

__device__ __forceinline__ float rcp_fast(float x) { return __builtin_amdgcn_rcpf(x); }
__device__ __forceinline__ float tanh_fast(float x) {
    float e = __expf(2.0f * x);
    return 1.0f - 2.0f * rcp_fast(e + 1.0f);
}
__device__ __forceinline__ u16 f2bf(float f) {
    unsigned int u = __float_as_uint(f);
    u = u + 0x7fffu + ((u >> 16) & 1u);
    return (u16)(u >> 16);
}
__device__ __forceinline__ float bf2f(u16 s) {
    return __uint_as_float(((unsigned int)s) << 16);
}

// ---------------------------------------------------------------------------
// Tables (one wave per h). INTERLEAVED n'' = 2n (re) / 2n+1 (im):
//  P_stack [128 n''][64 s] : [2n]=Re(Lam^{63-s}), [2n+1]=Im            (bf16 hi/lo)
//  G_stack [64 t][128 n''] : [2n]=2Re(CB Lam^{t+1}), [2n+1]=-2Im(...)  (bf16 hi/lo)
//  T       [64 t][64 s]    : K[t-s] (t>=s), K[d]=2Re(sum CB Lam^d)     (bf16 hi/lo)
//  L64     [n] = Lam_n^64                                              (f32)
// ---------------------------------------------------------------------------
__global__ __launch_bounds__(64) void tables2_kernel(
    const float* __restrict__ lre_g, const float* __restrict__ lim_g,
    const float* __restrict__ cbre_g, const float* __restrict__ cbim_g,
    u16* __restrict__ Phi, u16* __restrict__ Plo,
    u16* __restrict__ Ghi, u16* __restrict__ Glo,
    u16* __restrict__ Thi, u16* __restrict__ Tlo,
    float2* __restrict__ L64)
{
    __shared__ float Ksh[64];
    const int h = blockIdx.x, n = threadIdx.x;
    const float lr = lre_g[h * 64 + n], li = lim_g[h * 64 + n];
    const float cr = 2.0f * cbre_g[h * 64 + n];
    const float ci = 2.0f * cbim_g[h * 64 + n];

    u16* Ph = Phi + (size_t)h * 8192; u16* Pl = Plo + (size_t)h * 8192;
    u16* Gh = Ghi + (size_t)h * 8192; u16* Gl = Glo + (size_t)h * 8192;
    u16* Th = Thi + (size_t)h * 4096; u16* Tl = Tlo + (size_t)h * 4096;

    float qr = 1.0f, qi = 0.0f;                      // Lam^t
    for (int t = 0; t < 64; ++t) {
        float kp = cr * qr - ci * qi;                // 2Re(CB Lam^t)
        #pragma unroll
        for (int m = 32; m > 0; m >>= 1) kp += __shfl_xor(kp, m);
        if (n == 0) Ksh[t] = kp;

        int sre = (2 * n) * 64 + (63 - t), sim = (2 * n + 1) * 64 + (63 - t);
        u16 hre = f2bf(qr); Ph[sre] = hre; Pl[sre] = f2bf(qr - bf2f(hre));
        u16 him = f2bf(qi); Ph[sim] = him; Pl[sim] = f2bf(qi - bf2f(him));

        float nqr = qr * lr - qi * li;               // Lam^{t+1}
        float nqi = qr * li + qi * lr;
        qr = nqr; qi = nqi;

        float gre = cr * qr - ci * qi;               // 2Re(CB Lam^{t+1})
        float gim = cr * qi + ci * qr;               // 2Im(...)
        int o1 = t * 128 + 2 * n, o2 = o1 + 1;
        u16 g1 = f2bf(gre);  Gh[o1] = g1; Gl[o1] = f2bf(gre - bf2f(g1));
        float ngim = -gim;
        u16 g2 = f2bf(ngim); Gh[o2] = g2; Gl[o2] = f2bf(ngim - bf2f(g2));
    }
    L64[h * 64 + n] = make_float2(qr, qi);           // Lam^64
    __syncthreads();
    for (int r = 0; r < 64; ++r) {
        float val = (n <= r) ? Ksh[r - n] : 0.0f;
        u16 hv = f2bf(val);
        Th[r * 64 + n] = hv; Tl[r * 64 + n] = f2bf(val - bf2f(hv));
    }
}

// ---------------------------------------------------------------------------
// scan5: one block per (b,h), 4 waves. Retiled so each A-fragment feeds 2
// column-tiles:
//   V-phase: wave w owns mi = 4*(w>>1)..+3 (rows), ct = 2*(w&1)..+1 (cols)
//   Y-phase: wave w owns mi = 2*(w>>1)..+1,        ct = 2*(w&1)..+1
// LDS: aliased 65 x 512 B buffer (V row c+1 / X row c / Y row c). 3 barriers.
// ---------------------------------------------------------------------------
__global__ __launch_bounds__(256, 4) void scan5_kernel(
    const float* __restrict__ u,
    const float* __restrict__ Dg,
    const u16* __restrict__ Phi, const u16* __restrict__ Plo,
    const u16* __restrict__ Ghi, const u16* __restrict__ Glo,
    const u16* __restrict__ Thi, const u16* __restrict__ Tlo,
    const float2* __restrict__ L64,
    float* __restrict__ y)
{
    __shared__ __align__(16) char smem[65 * 512];

    const int bid = blockIdx.x;
    const int b = bid >> 8;
    const int h = ((bid >> 3) & 31) * 8 + (bid & 7);   // same-h blocks share an XCD
    const int tid = threadIdx.x;
    const int w = tid >> 6, l = tid & 63;
    const int l15 = l & 15, lhi = l >> 4;

    const int ctBase  = (w & 1) * 2;
    const int miBaseV = (w >> 1) * 4;
    const int miBaseY = (w >> 1) * 2;

    const float* urow = u + ((size_t)b * HDIM + h) * LDIM;

    // ---- U B-fragments for this wave's 2 col-tiles, direct from global ----
    int cBt[2];
    short8x ubh[2][2], ubl[2][2];                      // [ct2][ks]
    #pragma unroll
    for (int ct2 = 0; ct2 < 2; ++ct2) {
        cBt[ct2] = 16 * (ctBase + ct2) + l15;
        #pragma unroll
        for (int ks = 0; ks < 2; ++ks) {
            const float* src = urow + 64 * cBt[ct2] + 32 * ks + 8 * lhi;
            float4 f0 = *(const float4*)src;
            float4 f1 = *(const float4*)(src + 4);
            float fv[8] = {f0.x, f0.y, f0.z, f0.w, f1.x, f1.y, f1.z, f1.w};
            union { short8x v; u16 s[8]; } H, L;
            #pragma unroll
            for (int q = 0; q < 8; ++q) {
                u16 hq = f2bf(fv[q]);
                H.s[q] = hq; L.s[q] = f2bf(fv[q] - bf2f(hq));
            }
            ubh[ct2][ks] = H.v; ubl[ct2][ks] = L.v;
        }
    }

    // ---- V = P_stack x U : 4 mi x 2 ct per wave ----
    const u16* Ph = Phi + (size_t)h * 8192;
    const u16* Pl = Plo + (size_t)h * 8192;
    {
        f32x4 acc[4][2];
        #pragma unroll
        for (int m = 0; m < 4; ++m)
            #pragma unroll
            for (int c2 = 0; c2 < 2; ++c2)
                acc[m][c2] = (f32x4){0.0f, 0.0f, 0.0f, 0.0f};

        #pragma unroll
        for (int pair = 0; pair < 2; ++pair) {
            // batch-load 8 A-frags (2 mi x 2 ks x hi/lo)
            short8x pah[2][2], pal[2][2];              // [m][ks]
            #pragma unroll
            for (int m = 0; m < 2; ++m)
                #pragma unroll
                for (int ks = 0; ks < 2; ++ks) {
                    int off = (16 * (miBaseV + 2 * pair + m) + l15) * 64 + 32 * ks + 8 * lhi;
                    pah[m][ks] = *(const short8x*)(Ph + off);
                    pal[m][ks] = *(const short8x*)(Pl + off);
                }
            #pragma unroll
            for (int m = 0; m < 2; ++m)
                #pragma unroll
                for (int ks = 0; ks < 2; ++ks)
                    #pragma unroll
                    for (int c2 = 0; c2 < 2; ++c2) {
                        f32x4 a = acc[2 * pair + m][c2];
                        a = __builtin_amdgcn_mfma_f32_16x16x32_bf16(pah[m][ks], ubh[c2][ks], a, 0, 0, 0);
                        a = __builtin_amdgcn_mfma_f32_16x16x32_bf16(pah[m][ks], ubl[c2][ks], a, 0, 0, 0);
                        a = __builtin_amdgcn_mfma_f32_16x16x32_bf16(pal[m][ks], ubh[c2][ks], a, 0, 0, 0);
                        acc[2 * pair + m][c2] = a;
                    }
        }
        #pragma unroll
        for (int m = 0; m < 4; ++m)
            #pragma unroll
            for (int c2 = 0; c2 < 2; ++c2) {
                int rV = cBt[c2] + 1;
                int byte = 512 * rV + 64 * (miBaseV + m) + 16 * lhi;
                *(f32x4*)(smem + (byte ^ ((rV & 7) << 4))) = acc[m][c2];
            }
    }
    __syncthreads();

    // ---- serial chunk-state scan (wave 0, lane = n), V prefetched ----
    if (w == 0) {
        float2 lt = L64[h * 64 + l];
        float xr = 0.0f, xi = 0.0f;
        float2 v = *(const float2*)(smem + ((512 * 1 + 8 * l) ^ (1 << 4)));
        for (int c = 0; c < NCH; ++c) {
            int rn = (c < 62) ? c + 2 : 64;
            float2 vn = *(const float2*)(smem + ((512 * rn + 8 * l) ^ ((rn & 7) << 4)));
            int sw = (c & 7) << 4;
            u16 hr = f2bf(xr); u16 lr_ = f2bf(xr - bf2f(hr));
            u16 hi_ = f2bf(xi); u16 li_ = f2bf(xi - bf2f(hi_));
            *(u32*)(smem + ((512 * c + 4 * l) ^ sw))       = (u32)hr  | ((u32)hi_ << 16);
            *(u32*)(smem + ((512 * c + 256 + 4 * l) ^ sw)) = (u32)lr_ | ((u32)li_ << 16);
            float nr = fmaf(lt.x, xr, fmaf(-lt.y, xi, v.x));
            float ni = fmaf(lt.x, xi, fmaf( lt.y, xr, v.y));
            xr = nr; xi = ni;
            v = vn;
        }
    }
    __syncthreads();

    // ---- Y = G_stack x X + T x U : 2 mi x 2 ct per wave ----
    const u16* Gh_ = Ghi + (size_t)h * 8192;
    const u16* Gl_ = Glo + (size_t)h * 8192;
    const u16* Th_ = Thi + (size_t)h * 4096;
    const u16* Tl_ = Tlo + (size_t)h * 4096;
    {
        // X B-frags for 2 col-tiles (from this wave's own LDS rows)
        short8x xbh[2][4], xbl[2][4];                  // [ct2][ks]
        #pragma unroll
        for (int c2 = 0; c2 < 2; ++c2) {
            int swX = (cBt[c2] & 7) << 4;
            #pragma unroll
            for (int ks = 0; ks < 4; ++ks) {
                int byte = 512 * cBt[c2] + 64 * ks + 16 * lhi;
                xbh[c2][ks] = *(const short8x*)(smem + (byte ^ swX));
                xbl[c2][ks] = *(const short8x*)(smem + ((byte + 256) ^ swX));
            }
        }
        #pragma unroll
        for (int m = 0; m < 2; ++m) {
            const int mi = miBaseY + m;
            f32x4 acc[2];
            acc[0] = (f32x4){0.0f, 0.0f, 0.0f, 0.0f};
            acc[1] = (f32x4){0.0f, 0.0f, 0.0f, 0.0f};
            // batch-load G (8) then T (4) A-frags
            short8x gah[4], gal[4], tah[2], tal[2];
            #pragma unroll
            for (int ks = 0; ks < 4; ++ks) {
                int off = (16 * mi + l15) * 128 + 32 * ks + 8 * lhi;
                gah[ks] = *(const short8x*)(Gh_ + off);
                gal[ks] = *(const short8x*)(Gl_ + off);
            }
            #pragma unroll
            for (int ks = 0; ks < 2; ++ks) {
                int off = (16 * mi + l15) * 64 + 32 * ks + 8 * lhi;
                tah[ks] = *(const short8x*)(Th_ + off);
                tal[ks] = *(const short8x*)(Tl_ + off);
            }
            #pragma unroll
            for (int ks = 0; ks < 4; ++ks)
                #pragma unroll
                for (int c2 = 0; c2 < 2; ++c2) {
                    acc[c2] = __builtin_amdgcn_mfma_f32_16x16x32_bf16(gah[ks], xbh[c2][ks], acc[c2], 0, 0, 0);
                    acc[c2] = __builtin_amdgcn_mfma_f32_16x16x32_bf16(gah[ks], xbl[c2][ks], acc[c2], 0, 0, 0);
                    acc[c2] = __builtin_amdgcn_mfma_f32_16x16x32_bf16(gal[ks], xbh[c2][ks], acc[c2], 0, 0, 0);
                }
            #pragma unroll
            for (int ks = 0; ks < 2; ++ks)
                #pragma unroll
                for (int c2 = 0; c2 < 2; ++c2) {
                    acc[c2] = __builtin_amdgcn_mfma_f32_16x16x32_bf16(tah[ks], ubh[c2][ks], acc[c2], 0, 0, 0);
                    acc[c2] = __builtin_amdgcn_mfma_f32_16x16x32_bf16(tah[ks], ubl[c2][ks], acc[c2], 0, 0, 0);
                    acc[c2] = __builtin_amdgcn_mfma_f32_16x16x32_bf16(tal[ks], ubh[c2][ks], acc[c2], 0, 0, 0);
                }
            #pragma unroll
            for (int c2 = 0; c2 < 2; ++c2) {
                int byte = 512 * cBt[c2] + 64 * mi + 16 * lhi;
                *(f32x4*)(smem + (byte ^ ((cBt[c2] & 7) << 4))) = acc[c2];
            }
        }
    }
    __syncthreads();

    // ---- epilogue: y = tanh(Y + D*u), vectorized x4 ----
    const float Dh = Dg[h];
    float* yrow = y + ((size_t)b * HDIM + h) * LDIM;
    #pragma unroll
    for (int k = 0; k < 4; ++k) {
        int g4 = 1024 * k + 4 * tid;
        int c = g4 >> 6, t0 = g4 & 63;
        f32x4 yv = *(const f32x4*)(smem + ((512 * c + 4 * t0) ^ ((c & 7) << 4)));
        float4 uv = *(const float4*)(urow + g4);
        float4 o;
        o.x = tanh_fast(fmaf(Dh, uv.x, yv[0]));
        o.y = tanh_fast(fmaf(Dh, uv.y, yv[1]));
        o.z = tanh_fast(fmaf(Dh, uv.z, yv[2]));
        o.w = tanh_fast(fmaf(Dh, uv.w, yv[3]));
        *(float4*)(yrow + g4) = o;
    }
}

// ---------------------------------------------------------------------------
// W prep: Wp[r][h], r even -> W[r/2] (a-row), r odd -> W[r/2+256] (g-row);
// exact split into bf16 hi + lo, row-major [512][256].
// ---------------------------------------------------------------------------
__global__ __launch_bounds__(256) void prep_w(
    const float* __restrict__ W, u16* __restrict__ Wphi, u16* __restrict__ Wplo)
{
    const int r = blockIdx.x, hcol = threadIdx.x;
    const int src = (r & 1) ? (r >> 1) + 256 : (r >> 1);
    float v = W[src * 256 + hcol];
    u16 hv = f2bf(v);
    Wphi[r * 256 + hcol] = hv;
    Wplo[r * 256 + hcol] = f2bf(v - bf2f(hv));
}

// ---------------------------------------------------------------------------
// mix3: MFMA mix + GLU. 512 threads / 8 waves; BM=512 rows (wave w owns
// 64 rows), BN=64 cols; K=256 in 4 steps of 64. Y staged bf16 in LDS
// [col][k] XOR-swizzled. Each W A-frag feeds 4 col-tiles (64 MFMA / 16 loads
// per K-step). In-place on d_out: block touches only its (b, col-slice).
// ---------------------------------------------------------------------------
__global__ __launch_bounds__(512, 4) void mix3_kernel(
    const float* y,                        // d_out: scan output [B][256][4096]
    const u16* __restrict__ Wphi, const u16* __restrict__ Wplo,
    const float* __restrict__ bm,
    float* out)                            // d_out (aliases y)
{
    __shared__ __align__(16) u16 Ysh[64 * 64];     // 8 KB, [col][k] swizzled

    const int tid = threadIdx.x;
    const int w = tid >> 6, l = tid & 63;
    const int l15 = l & 15, lhi = l >> 4;
    const int b = blockIdx.y;
    const int col0 = blockIdx.x * 64;

    const float* Yb = y + ((size_t)b * HDIM) * LDIM;

    const int p  = tid >> 4;               // k-pair 0..31
    const int cg = tid & 15;               // col-group of 4

    f32x4 acc[4][4];                       // [mi][ct]
    #pragma unroll
    for (int mi = 0; mi < 4; ++mi)
        #pragma unroll
        for (int ct = 0; ct < 4; ++ct)
            acc[mi][ct] = (f32x4){0.0f, 0.0f, 0.0f, 0.0f};

    for (int kb = 0; kb < 4; ++kb) {
        const int k0 = kb * 64;
        // ---- stage Y[k0..k0+63][col0..col0+63] -> bf16 LDS [col][k] ----
        const float* r0 = Yb + (size_t)(k0 + 2 * p) * LDIM + col0 + 4 * cg;
        float4 f0 = *(const float4*)r0;
        float4 f1 = *(const float4*)(r0 + LDIM);
        float f0v[4] = {f0.x, f0.y, f0.z, f0.w};
        float f1v[4] = {f1.x, f1.y, f1.z, f1.w};
        #pragma unroll
        for (int q = 0; q < 4; ++q) {
            int col = 4 * cg + q;
            u32 wv = (u32)f2bf(f0v[q]) | ((u32)f2bf(f1v[q]) << 16);
            int byte = (col * 128 + 4 * p) ^ ((col & 7) << 4);
            *(u32*)((char*)Ysh + byte) = wv;
        }
        __syncthreads();

        // ---- compute: 4 mi x 4 ct, W A-frags batch-loaded per mi ----
        #pragma unroll
        for (int mi = 0; mi < 4; ++mi) {
            const size_t row = (size_t)(64 * w + 16 * mi + l15);
            short8x wh[2], wl[2];
            #pragma unroll
            for (int ks = 0; ks < 2; ++ks) {
                size_t off = row * 256 + k0 + 32 * ks + 8 * lhi;
                wh[ks] = *(const short8x*)(Wphi + off);
                wl[ks] = *(const short8x*)(Wplo + off);
            }
            #pragma unroll
            for (int ct = 0; ct < 4; ++ct) {
                #pragma unroll
                for (int ks = 0; ks < 2; ++ks) {
                    int col = 16 * ct + l15;
                    int byte = (col * 128 + 64 * ks + 16 * lhi) ^ ((col & 7) << 4);
                    short8x yb = *(const short8x*)((char*)Ysh + byte);
                    acc[mi][ct] = __builtin_amdgcn_mfma_f32_16x16x32_bf16(wh[ks], yb, acc[mi][ct], 0, 0, 0);
                    acc[mi][ct] = __builtin_amdgcn_mfma_f32_16x16x32_bf16(wl[ks], yb, acc[mi][ct], 0, 0, 0);
                }
            }
        }
        __syncthreads();
    }

    // ---- epilogue: bias + GLU + store ----
    float* ob = out + ((size_t)b * HDIM) * LDIM;
    #pragma unroll
    for (int mi = 0; mi < 4; ++mi) {
        int r0 = 64 * w + 16 * mi + 4 * lhi;   // multiple of 4
        int h1 = r0 >> 1;
        float ba1 = bm[h1],     bg1 = bm[h1 + 256];
        float ba2 = bm[h1 + 1], bg2 = bm[h1 + 1 + 256];
        #pragma unroll
        for (int ct = 0; ct < 4; ++ct) {
            f32x4 a = acc[mi][ct];
            int col = col0 + 16 * ct + l15;
            float A1 = a[0] + ba1, G1 = a[1] + bg1;
            float A2 = a[2] + ba2, G2 = a[3] + bg2;
            ob[(size_t)h1 * LDIM + col]       = A1 * rcp_fast(1.0f + __expf(-G1));
            ob[(size_t)(h1 + 1) * LDIM + col] = A2 * rcp_fast(1.0f + __expf(-G2));
        }
    }
}

// ---------------------------------------------------------------------------
extern "C" void kernel_launch(void* const* d_in, const int* in_sizes, int n_in,
                              void* d_out, int out_size, void* d_ws, size_t ws_size,
                              hipStream_t stream)
{
    const float* u    = (const float*)d_in[0];
    const float* lre  = (const float*)d_in[1];
    const float* lim  = (const float*)d_in[2];
    const float* cbre = (const float*)d_in[3];
    const float* cbim = (const float*)d_in[4];
    const float* Dg   = (const float*)d_in[5];
    const float* W    = (const float*)d_in[6];
    const float* bm   = (const float*)d_in[7];
    float* out = (float*)d_out;

    char* ws = (char*)d_ws;
    size_t o = 0;
    u16* Wphi = (u16*)(ws + o); o += (size_t)1 << 18;      // 256 KB
    u16* Wplo = (u16*)(ws + o); o += (size_t)1 << 18;      // 256 KB
    u16* Phi = (u16*)(ws + o); o += (size_t)1 << 22;       // 4 MB each
    u16* Plo = (u16*)(ws + o); o += (size_t)1 << 22;
    u16* Ghi = (u16*)(ws + o); o += (size_t)1 << 22;
    u16* Glo = (u16*)(ws + o); o += (size_t)1 << 22;
    u16* Thi = (u16*)(ws + o); o += (size_t)1 << 21;       // 2 MB each
    u16* Tlo = (u16*)(ws + o); o += (size_t)1 << 21;
    float2* L64 = (float2*)(ws + o);                       // 128 KB

    tables2_kernel<<<HDIM, 64, 0, stream>>>(lre, lim, cbre, cbim,
                                            Phi, Plo, Ghi, Glo, Thi, Tlo, L64);
    prep_w<<<512, 256, 0, stream>>>(W, Wphi, Wplo);
    scan5_kernel<<<BDIM * HDIM, 256, 0, stream>>>(u, Dg, Phi, Plo, Ghi, Glo,
                                                  Thi, Tlo, L64, out);
    dim3 grid(LDIM / 64, BDIM);
    mix3_kernel<<<grid, 512, 0, stream>>>(out, Wphi, Wplo, bm, out);
}

// Round 7
// 133.180 us; speedup vs baseline: 5.4628x; 1.0187x over previous
//
#include <hip/hip_runtime.h>
#include <hip/hip_bf16.h>
#include <cmath>

#define BDIM 8
#define HDIM 256
#define LDIM 4096
#define NDIM 64
#define TCH  64
#define NCH  64

typedef unsigned short u16;
typedef unsigned int   u32;
typedef __attribute__((ext_vector_type(8))) short short8x;
typedef __attribute__((ext_vector_type(4))) float f32x4;

__device__ __forceinline__ float rcp_fast(float x) { return __builtin_amdgcn_rcpf(x); }
__device__ __forceinline__ float tanh_fast(float x) {
    float e = __expf(2.0f * x);
    return 1.0f - 2.0f * rcp_fast(e + 1.0f);
}
__device__ __forceinline__ u16 f2bf(float f) {
    unsigned int u = __float_as_uint(f);
    u = u + 0x7fffu + ((u >> 16) & 1u);
    return (u16)(u >> 16);
}
__device__ __forceinline__ float bf2f(u16 s) {
    return __uint_as_float(((unsigned int)s) << 16);
}

// ---------------------------------------------------------------------------
// tables3: 4 waves per h; wave w handles t in [16w, 16w+16). Lane = n.
// Start state Lam^{16w} via 4 squarings + <=7 wave-uniform cmuls.
//  P_stack [128 n''][64 s] : [2n]=Re(Lam^{63-s}), [2n+1]=Im            (bf16 hi/lo)
//  G_stack [64 t][128 n''] : [2n]=2Re(CB Lam^{t+1}), [2n+1]=-2Im(...)  (bf16 hi/lo)
//  T       [64 t][64 s]    : K[t-s] (t>=s)                             (bf16 hi/lo)
//  L64     [n] = Lam_n^64                                              (f32)
// ---------------------------------------------------------------------------
__global__ __launch_bounds__(256) void tables3_kernel(
    const float* __restrict__ lre_g, const float* __restrict__ lim_g,
    const float* __restrict__ cbre_g, const float* __restrict__ cbim_g,
    u16* __restrict__ Phi, u16* __restrict__ Plo,
    u16* __restrict__ Ghi, u16* __restrict__ Glo,
    u16* __restrict__ Thi, u16* __restrict__ Tlo,
    float2* __restrict__ L64)
{
    __shared__ float Ksh[64];
    const int h = blockIdx.x;
    const int tid = threadIdx.x;
    const int w = tid >> 6;                 // t-block 0..3
    const int n = tid & 63;

    const float lr = lre_g[h * 64 + n], li = lim_g[h * 64 + n];
    const float cr = 2.0f * cbre_g[h * 64 + n];
    const float ci = 2.0f * cbim_g[h * 64 + n];

    u16* Ph = Phi + (size_t)h * 8192; u16* Pl = Plo + (size_t)h * 8192;
    u16* Gh = Ghi + (size_t)h * 8192; u16* Gl = Glo + (size_t)h * 8192;
    u16* Th = Thi + (size_t)h * 4096; u16* Tl = Tlo + (size_t)h * 4096;

    // s = Lam^16
    float sr = lr, si = li;
    #pragma unroll
    for (int j = 0; j < 4; ++j) {
        float tr = sr * sr - si * si;
        si = 2.0f * sr * si; sr = tr;
    }
    // q = Lam^{16w}  (trip count wave-uniform)
    float qr = 1.0f, qi = 0.0f;
    for (int j = 0; j < w; ++j) {
        float tr = qr * sr - qi * si;
        qi = qr * si + qi * sr; qr = tr;
    }

    #pragma unroll
    for (int j = 0; j < 16; ++j) {
        const int t = 16 * w + j;
        float kp = cr * qr - ci * qi;                // 2Re(CB Lam^t)
        #pragma unroll
        for (int m = 32; m > 0; m >>= 1) kp += __shfl_xor(kp, m);
        if (n == 0) Ksh[t] = kp;

        int sre = (2 * n) * 64 + (63 - t), sim = (2 * n + 1) * 64 + (63 - t);
        u16 hre = f2bf(qr); Ph[sre] = hre; Pl[sre] = f2bf(qr - bf2f(hre));
        u16 him = f2bf(qi); Ph[sim] = him; Pl[sim] = f2bf(qi - bf2f(him));

        float nqr = qr * lr - qi * li;               // Lam^{t+1}
        float nqi = qr * li + qi * lr;
        qr = nqr; qi = nqi;

        float gre = cr * qr - ci * qi;
        float gim = cr * qi + ci * qr;
        int o1 = t * 128 + 2 * n, o2 = o1 + 1;
        u16 g1 = f2bf(gre);  Gh[o1] = g1; Gl[o1] = f2bf(gre - bf2f(g1));
        float ngim = -gim;
        u16 g2 = f2bf(ngim); Gh[o2] = g2; Gl[o2] = f2bf(ngim - bf2f(g2));
    }
    if (w == 3) L64[h * 64 + n] = make_float2(qr, qi);   // Lam^64
    __syncthreads();

    // T build: thread -> row r = tid>>2, cols 16*(tid&3)..+15
    const int r = tid >> 2, c0 = (tid & 3) * 16;
    #pragma unroll
    for (int i = 0; i < 16; ++i) {
        int c = c0 + i;
        float val = (c <= r) ? Ksh[r - c] : 0.0f;
        u16 hv = f2bf(val);
        Th[r * 64 + c] = hv; Tl[r * 64 + c] = f2bf(val - bf2f(hv));
    }
}

// ---------------------------------------------------------------------------
// scan6: one block per (b,h), 4 waves. A-frags amortized over ALL 4 col-tiles:
//   V-phase: wave w owns mi in {2w,2w+1} x ct 0..3   (8 A-loads -> 48 MFMA)
//   Y-phase: wave w owns mi = w        x ct 0..3   (12 A-loads -> 72 MFMA)
// LDS: aliased 65 x 512 B buffer (V row c+1 / X row c / Y row c). 4 barriers.
// Y results held in regs across a barrier (cts shared by all waves now).
// ---------------------------------------------------------------------------
__global__ __launch_bounds__(256, 3) void scan6_kernel(
    const float* __restrict__ u,
    const float* __restrict__ Dg,
    const u16* __restrict__ Phi, const u16* __restrict__ Plo,
    const u16* __restrict__ Ghi, const u16* __restrict__ Glo,
    const u16* __restrict__ Thi, const u16* __restrict__ Tlo,
    const float2* __restrict__ L64,
    float* __restrict__ y)
{
    __shared__ __align__(16) char smem[65 * 512];

    const int bid = blockIdx.x;
    const int b = bid >> 8;
    const int h = ((bid >> 3) & 31) * 8 + (bid & 7);   // same-h blocks share an XCD
    const int tid = threadIdx.x;
    const int w = tid >> 6, l = tid & 63;
    const int l15 = l & 15, lhi = l >> 4;

    const float* urow = u + ((size_t)b * HDIM + h) * LDIM;

    // ---- V = P_stack x U : wave w -> mi {2w,2w+1}, all 4 ct ----
    const u16* Ph = Phi + (size_t)h * 8192;
    const u16* Pl = Plo + (size_t)h * 8192;
    {
        short8x pah[2][2], pal[2][2];
        #pragma unroll
        for (int m = 0; m < 2; ++m)
            #pragma unroll
            for (int ks = 0; ks < 2; ++ks) {
                int off = (16 * (2 * w + m) + l15) * 64 + 32 * ks + 8 * lhi;
                pah[m][ks] = *(const short8x*)(Ph + off);
                pal[m][ks] = *(const short8x*)(Pl + off);
            }
        f32x4 acc[2][4];
        #pragma unroll
        for (int m = 0; m < 2; ++m)
            #pragma unroll
            for (int c = 0; c < 4; ++c)
                acc[m][c] = (f32x4){0.0f, 0.0f, 0.0f, 0.0f};

        #pragma unroll
        for (int cp = 0; cp < 2; ++cp) {
            short8x ubh[2][2], ubl[2][2];
            #pragma unroll
            for (int c2 = 0; c2 < 2; ++c2) {
                int cB = 16 * (2 * cp + c2) + l15;
                #pragma unroll
                for (int ks = 0; ks < 2; ++ks) {
                    const float* src = urow + 64 * cB + 32 * ks + 8 * lhi;
                    float4 f0 = *(const float4*)src;
                    float4 f1 = *(const float4*)(src + 4);
                    float fv[8] = {f0.x, f0.y, f0.z, f0.w, f1.x, f1.y, f1.z, f1.w};
                    union { short8x v; u16 s[8]; } H, L;
                    #pragma unroll
                    for (int q = 0; q < 8; ++q) {
                        u16 hq = f2bf(fv[q]);
                        H.s[q] = hq; L.s[q] = f2bf(fv[q] - bf2f(hq));
                    }
                    ubh[c2][ks] = H.v; ubl[c2][ks] = L.v;
                }
            }
            #pragma unroll
            for (int m = 0; m < 2; ++m)
                #pragma unroll
                for (int ks = 0; ks < 2; ++ks)
                    #pragma unroll
                    for (int c2 = 0; c2 < 2; ++c2) {
                        f32x4 a = acc[m][2 * cp + c2];
                        a = __builtin_amdgcn_mfma_f32_16x16x32_bf16(pah[m][ks], ubh[c2][ks], a, 0, 0, 0);
                        a = __builtin_amdgcn_mfma_f32_16x16x32_bf16(pah[m][ks], ubl[c2][ks], a, 0, 0, 0);
                        a = __builtin_amdgcn_mfma_f32_16x16x32_bf16(pal[m][ks], ubh[c2][ks], a, 0, 0, 0);
                        acc[m][2 * cp + c2] = a;
                    }
        }
        #pragma unroll
        for (int m = 0; m < 2; ++m)
            #pragma unroll
            for (int ct = 0; ct < 4; ++ct) {
                int rV = 16 * ct + l15 + 1;
                int byte = 512 * rV + 64 * (2 * w + m) + 16 * lhi;
                *(f32x4*)(smem + (byte ^ ((rV & 7) << 4))) = acc[m][ct];
            }
    }
    __syncthreads();

    // ---- serial chunk-state scan (wave 0, lane = n), V prefetched ----
    if (w == 0) {
        float2 lt = L64[h * 64 + l];
        float xr = 0.0f, xi = 0.0f;
        float2 v = *(const float2*)(smem + ((512 * 1 + 8 * l) ^ (1 << 4)));
        for (int c = 0; c < NCH; ++c) {
            int rn = (c < 62) ? c + 2 : 64;
            float2 vn = *(const float2*)(smem + ((512 * rn + 8 * l) ^ ((rn & 7) << 4)));
            int sw = (c & 7) << 4;
            u16 hr = f2bf(xr); u16 lr_ = f2bf(xr - bf2f(hr));
            u16 hi_ = f2bf(xi); u16 li_ = f2bf(xi - bf2f(hi_));
            *(u32*)(smem + ((512 * c + 4 * l) ^ sw))       = (u32)hr  | ((u32)hi_ << 16);
            *(u32*)(smem + ((512 * c + 256 + 4 * l) ^ sw)) = (u32)lr_ | ((u32)li_ << 16);
            float nr = fmaf(lt.x, xr, fmaf(-lt.y, xi, v.x));
            float ni = fmaf(lt.x, xi, fmaf( lt.y, xr, v.y));
            xr = nr; xi = ni;
            v = vn;
        }
    }
    __syncthreads();

    // ---- Y = G_stack x X + T x U : wave w -> mi = w, all 4 ct ----
    const u16* Gh_ = Ghi + (size_t)h * 8192;
    const u16* Gl_ = Glo + (size_t)h * 8192;
    const u16* Th_ = Thi + (size_t)h * 4096;
    const u16* Tl_ = Tlo + (size_t)h * 4096;
    {
        short8x gah[4], gal[4], tah[2], tal[2];
        #pragma unroll
        for (int ks = 0; ks < 4; ++ks) {
            int off = (16 * w + l15) * 128 + 32 * ks + 8 * lhi;
            gah[ks] = *(const short8x*)(Gh_ + off);
            gal[ks] = *(const short8x*)(Gl_ + off);
        }
        #pragma unroll
        for (int ks = 0; ks < 2; ++ks) {
            int off = (16 * w + l15) * 64 + 32 * ks + 8 * lhi;
            tah[ks] = *(const short8x*)(Th_ + off);
            tal[ks] = *(const short8x*)(Tl_ + off);
        }

        f32x4 acc[4];
        #pragma unroll
        for (int ct = 0; ct < 4; ++ct) {
            const int cB = 16 * ct + l15;
            const int swX = (cB & 7) << 4;
            // X B-frags (LDS)
            short8x xbh[4], xbl[4];
            #pragma unroll
            for (int ks = 0; ks < 4; ++ks) {
                int byte = 512 * cB + 64 * ks + 16 * lhi;
                xbh[ks] = *(const short8x*)(smem + (byte ^ swX));
                xbl[ks] = *(const short8x*)(smem + ((byte + 256) ^ swX));
            }
            // U B-frags (reload from global; L1/L2-hot)
            short8x ubh2[2], ubl2[2];
            #pragma unroll
            for (int ks = 0; ks < 2; ++ks) {
                const float* src = urow + 64 * cB + 32 * ks + 8 * lhi;
                float4 f0 = *(const float4*)src;
                float4 f1 = *(const float4*)(src + 4);
                float fv[8] = {f0.x, f0.y, f0.z, f0.w, f1.x, f1.y, f1.z, f1.w};
                union { short8x v; u16 s[8]; } H, L;
                #pragma unroll
                for (int q = 0; q < 8; ++q) {
                    u16 hq = f2bf(fv[q]);
                    H.s[q] = hq; L.s[q] = f2bf(fv[q] - bf2f(hq));
                }
                ubh2[ks] = H.v; ubl2[ks] = L.v;
            }
            f32x4 a = {0.0f, 0.0f, 0.0f, 0.0f};
            #pragma unroll
            for (int ks = 0; ks < 4; ++ks) {
                a = __builtin_amdgcn_mfma_f32_16x16x32_bf16(gah[ks], xbh[ks], a, 0, 0, 0);
                a = __builtin_amdgcn_mfma_f32_16x16x32_bf16(gah[ks], xbl[ks], a, 0, 0, 0);
                a = __builtin_amdgcn_mfma_f32_16x16x32_bf16(gal[ks], xbh[ks], a, 0, 0, 0);
            }
            #pragma unroll
            for (int ks = 0; ks < 2; ++ks) {
                a = __builtin_amdgcn_mfma_f32_16x16x32_bf16(tah[ks], ubh2[ks], a, 0, 0, 0);
                a = __builtin_amdgcn_mfma_f32_16x16x32_bf16(tah[ks], ubl2[ks], a, 0, 0, 0);
                a = __builtin_amdgcn_mfma_f32_16x16x32_bf16(tal[ks], ubh2[ks], a, 0, 0, 0);
            }
            acc[ct] = a;
        }
        __syncthreads();   // all waves' X reads done before Y overwrites
        #pragma unroll
        for (int ct = 0; ct < 4; ++ct) {
            int cB = 16 * ct + l15;
            int byte = 512 * cB + 64 * w + 16 * lhi;
            *(f32x4*)(smem + (byte ^ ((cB & 7) << 4))) = acc[ct];
        }
    }
    __syncthreads();

    // ---- epilogue: y = tanh(Y + D*u), vectorized x4 ----
    const float Dh = Dg[h];
    float* yrow = y + ((size_t)b * HDIM + h) * LDIM;
    #pragma unroll
    for (int k = 0; k < 4; ++k) {
        int g4 = 1024 * k + 4 * tid;
        int c = g4 >> 6, t0 = g4 & 63;
        f32x4 yv = *(const f32x4*)(smem + ((512 * c + 4 * t0) ^ ((c & 7) << 4)));
        float4 uv = *(const float4*)(urow + g4);
        float4 o;
        o.x = tanh_fast(fmaf(Dh, uv.x, yv[0]));
        o.y = tanh_fast(fmaf(Dh, uv.y, yv[1]));
        o.z = tanh_fast(fmaf(Dh, uv.z, yv[2]));
        o.w = tanh_fast(fmaf(Dh, uv.w, yv[3]));
        *(float4*)(yrow + g4) = o;
    }
}

// ---------------------------------------------------------------------------
// W prep: Wp[r][h], r even -> W[r/2] (a-row), r odd -> W[r/2+256] (g-row);
// exact split into bf16 hi + lo, row-major [512][256].
// ---------------------------------------------------------------------------
__global__ __launch_bounds__(256) void prep_w(
    const float* __restrict__ W, u16* __restrict__ Wphi, u16* __restrict__ Wplo)
{
    const int r = blockIdx.x, hcol = threadIdx.x;
    const int src = (r & 1) ? (r >> 1) + 256 : (r >> 1);
    float v = W[src * 256 + hcol];
    u16 hv = f2bf(v);
    Wphi[r * 256 + hcol] = hv;
    Wplo[r * 256 + hcol] = f2bf(v - bf2f(hv));
}

// ---------------------------------------------------------------------------
// mix4: MFMA mix + GLU. 512 threads / 8 waves; BM=512 rows (wave w owns
// 64 rows = 4 mi), BN=128 cols (8 ct); K=256 in 4 steps of 64. Y staged bf16
// in LDS [col][k] XOR-swizzled. Per K-step: 16 W-loads feed 128 MFMAs/wave.
// Grid 32 x 8 = 256 blocks = 1/CU. In-place on d_out (block-exclusive slice).
// ---------------------------------------------------------------------------
__global__ __launch_bounds__(512, 2) void mix4_kernel(
    const float* y,                        // d_out: scan output [B][256][4096]
    const u16* __restrict__ Wphi, const u16* __restrict__ Wplo,
    const float* __restrict__ bm,
    float* out)                            // d_out (aliases y)
{
    __shared__ __align__(16) u16 Ysh[128 * 64];    // 16 KB, [col][k] swizzled

    const int tid = threadIdx.x;
    const int w = tid >> 6, l = tid & 63;
    const int l15 = l & 15, lhi = l >> 4;
    const int b = blockIdx.y;
    const int col0 = blockIdx.x * 128;

    const float* Yb = y + ((size_t)b * HDIM) * LDIM;

    const int p  = tid >> 4;               // k-pair 0..31
    const int cg = tid & 15;               // col-group of 8

    f32x4 acc[4][8];                       // [mi][ct]
    #pragma unroll
    for (int mi = 0; mi < 4; ++mi)
        #pragma unroll
        for (int ct = 0; ct < 8; ++ct)
            acc[mi][ct] = (f32x4){0.0f, 0.0f, 0.0f, 0.0f};

    for (int kb = 0; kb < 4; ++kb) {
        const int k0 = kb * 64;
        // ---- stage Y[k0..k0+63][col0..col0+127] -> bf16 LDS [col][k] ----
        const float* r0 = Yb + (size_t)(k0 + 2 * p) * LDIM + col0 + 8 * cg;
        float4 a0 = *(const float4*)r0;
        float4 a1 = *(const float4*)(r0 + 4);
        float4 b0 = *(const float4*)(r0 + LDIM);
        float4 b1 = *(const float4*)(r0 + LDIM + 4);
        float f0v[8] = {a0.x, a0.y, a0.z, a0.w, a1.x, a1.y, a1.z, a1.w};
        float f1v[8] = {b0.x, b0.y, b0.z, b0.w, b1.x, b1.y, b1.z, b1.w};
        #pragma unroll
        for (int q = 0; q < 8; ++q) {
            int col = 8 * cg + q;
            u32 wv = (u32)f2bf(f0v[q]) | ((u32)f2bf(f1v[q]) << 16);
            int byte = (col * 128 + 4 * p) ^ ((col & 7) << 4);
            *(u32*)((char*)Ysh + byte) = wv;
        }
        __syncthreads();

        // ---- compute: 4 mi x 8 ct, W A-frags batch-loaded per mi ----
        #pragma unroll
        for (int mi = 0; mi < 4; ++mi) {
            const size_t row = (size_t)(64 * w + 16 * mi + l15);
            short8x wh[2], wl[2];
            #pragma unroll
            for (int ks = 0; ks < 2; ++ks) {
                size_t off = row * 256 + k0 + 32 * ks + 8 * lhi;
                wh[ks] = *(const short8x*)(Wphi + off);
                wl[ks] = *(const short8x*)(Wplo + off);
            }
            #pragma unroll
            for (int ct = 0; ct < 8; ++ct) {
                #pragma unroll
                for (int ks = 0; ks < 2; ++ks) {
                    int col = 16 * ct + l15;
                    int byte = (col * 128 + 64 * ks + 16 * lhi) ^ ((col & 7) << 4);
                    short8x yb = *(const short8x*)((char*)Ysh + byte);
                    acc[mi][ct] = __builtin_amdgcn_mfma_f32_16x16x32_bf16(wh[ks], yb, acc[mi][ct], 0, 0, 0);
                    acc[mi][ct] = __builtin_amdgcn_mfma_f32_16x16x32_bf16(wl[ks], yb, acc[mi][ct], 0, 0, 0);
                }
            }
        }
        __syncthreads();
    }

    // ---- epilogue: bias + GLU + store ----
    float* ob = out + ((size_t)b * HDIM) * LDIM;
    #pragma unroll
    for (int mi = 0; mi < 4; ++mi) {
        int r0 = 64 * w + 16 * mi + 4 * lhi;   // multiple of 4
        int h1 = r0 >> 1;
        float ba1 = bm[h1],     bg1 = bm[h1 + 256];
        float ba2 = bm[h1 + 1], bg2 = bm[h1 + 1 + 256];
        #pragma unroll
        for (int ct = 0; ct < 8; ++ct) {
            f32x4 a = acc[mi][ct];
            int col = col0 + 16 * ct + l15;
            float A1 = a[0] + ba1, G1 = a[1] + bg1;
            float A2 = a[2] + ba2, G2 = a[3] + bg2;
            ob[(size_t)h1 * LDIM + col]       = A1 * rcp_fast(1.0f + __expf(-G1));
            ob[(size_t)(h1 + 1) * LDIM + col] = A2 * rcp_fast(1.0f + __expf(-G2));
        }
    }
}

// ---------------------------------------------------------------------------
extern "C" void kernel_launch(void* const* d_in, const int* in_sizes, int n_in,
                              void* d_out, int out_size, void* d_ws, size_t ws_size,
                              hipStream_t stream)
{
    const float* u    = (const float*)d_in[0];
    const float* lre  = (const float*)d_in[1];
    const float* lim  = (const float*)d_in[2];
    const float* cbre = (const float*)d_in[3];
    const float* cbim = (const float*)d_in[4];
    const float* Dg   = (const float*)d_in[5];
    const float* W    = (const float*)d_in[6];
    const float* bm   = (const float*)d_in[7];
    float* out = (float*)d_out;

    char* ws = (char*)d_ws;
    size_t o = 0;
    u16* Wphi = (u16*)(ws + o); o += (size_t)1 << 18;      // 256 KB
    u16* Wplo = (u16*)(ws + o); o += (size_t)1 << 18;      // 256 KB
    u16* Phi = (u16*)(ws + o); o += (size_t)1 << 22;       // 4 MB each
    u16* Plo = (u16*)(ws + o); o += (size_t)1 << 22;
    u16* Ghi = (u16*)(ws + o); o += (size_t)1 << 22;
    u16* Glo = (u16*)(ws + o); o += (size_t)1 << 22;
    u16* Thi = (u16*)(ws + o); o += (size_t)1 << 21;       // 2 MB each
    u16* Tlo = (u16*)(ws + o); o += (size_t)1 << 21;
    float2* L64 = (float2*)(ws + o);                       // 128 KB

    tables3_kernel<<<HDIM, 256, 0, stream>>>(lre, lim, cbre, cbim,
                                             Phi, Plo, Ghi, Glo, Thi, Tlo, L64);
    prep_w<<<512, 256, 0, stream>>>(W, Wphi, Wplo);
    scan6_kernel<<<BDIM * HDIM, 256, 0, stream>>>(u, Dg, Phi, Plo, Ghi, Glo,
                                                  Thi, Tlo, L64, out);
    dim3 grid(LDIM / 128, BDIM);
    mix4_kernel<<<grid, 512, 0, stream>>>(out, Wphi, Wplo, bm, out);
}

// Round 8
// 119.584 us; speedup vs baseline: 6.0839x; 1.1137x over previous
//
#include <hip/hip_runtime.h>
#include <hip/hip_bf16.h>
#include <cmath>

#define BDIM 8
#define HDIM 256
#define LDIM 4096
#define NDIM 64
#define TCH  64
#define NCH  64

typedef unsigned short u16;
typedef unsigned int   u32;
typedef __attribute__((ext_vector_type(8))) short short8x;
typedef __attribute__((ext_vector_type(4))) float f32x4;

__device__ __forceinline__ float rcp_fast(float x) { return __builtin_amdgcn_rcpf(x); }
__device__ __forceinline__ float tanh_fast(float x) {
    float e = __expf(2.0f * x);
    return 1.0f - 2.0f * rcp_fast(e + 1.0f);
}
__device__ __forceinline__ u16 f2bf(float f) {
    unsigned int u = __float_as_uint(f);
    u = u + 0x7fffu + ((u >> 16) & 1u);
    return (u16)(u >> 16);
}
__device__ __forceinline__ float bf2f(u16 s) {
    return __uint_as_float(((unsigned int)s) << 16);
}

// ---------------------------------------------------------------------------
// tables3: 4 waves per h; wave w handles t in [16w, 16w+16). Lane = n.
//  P_stack [128 n''][64 s] : [2n]=Re(Lam^{63-s}), [2n+1]=Im            (bf16 hi/lo)
//  G_stack [64 t][128 n''] : [2n]=2Re(CB Lam^{t+1}), [2n+1]=-2Im(...)  (bf16 hi/lo)
//  T       [64 t][64 s]    : K[t-s] (t>=s)                             (bf16 hi/lo)
//  L64     [n] = Lam_n^64                                              (f32)
// ---------------------------------------------------------------------------
__global__ __launch_bounds__(256) void tables3_kernel(
    const float* __restrict__ lre_g, const float* __restrict__ lim_g,
    const float* __restrict__ cbre_g, const float* __restrict__ cbim_g,
    u16* __restrict__ Phi, u16* __restrict__ Plo,
    u16* __restrict__ Ghi, u16* __restrict__ Glo,
    u16* __restrict__ Thi, u16* __restrict__ Tlo,
    float2* __restrict__ L64)
{
    __shared__ float Ksh[64];
    const int h = blockIdx.x;
    const int tid = threadIdx.x;
    const int w = tid >> 6;                 // t-block 0..3
    const int n = tid & 63;

    const float lr = lre_g[h * 64 + n], li = lim_g[h * 64 + n];
    const float cr = 2.0f * cbre_g[h * 64 + n];
    const float ci = 2.0f * cbim_g[h * 64 + n];

    u16* Ph = Phi + (size_t)h * 8192; u16* Pl = Plo + (size_t)h * 8192;
    u16* Gh = Ghi + (size_t)h * 8192; u16* Gl = Glo + (size_t)h * 8192;
    u16* Th = Thi + (size_t)h * 4096; u16* Tl = Tlo + (size_t)h * 4096;

    // s = Lam^16
    float sr = lr, si = li;
    #pragma unroll
    for (int j = 0; j < 4; ++j) {
        float tr = sr * sr - si * si;
        si = 2.0f * sr * si; sr = tr;
    }
    // q = Lam^{16w}
    float qr = 1.0f, qi = 0.0f;
    for (int j = 0; j < w; ++j) {
        float tr = qr * sr - qi * si;
        qi = qr * si + qi * sr; qr = tr;
    }

    #pragma unroll
    for (int j = 0; j < 16; ++j) {
        const int t = 16 * w + j;
        float kp = cr * qr - ci * qi;                // 2Re(CB Lam^t)
        #pragma unroll
        for (int m = 32; m > 0; m >>= 1) kp += __shfl_xor(kp, m);
        if (n == 0) Ksh[t] = kp;

        int sre = (2 * n) * 64 + (63 - t), sim = (2 * n + 1) * 64 + (63 - t);
        u16 hre = f2bf(qr); Ph[sre] = hre; Pl[sre] = f2bf(qr - bf2f(hre));
        u16 him = f2bf(qi); Ph[sim] = him; Pl[sim] = f2bf(qi - bf2f(him));

        float nqr = qr * lr - qi * li;               // Lam^{t+1}
        float nqi = qr * li + qi * lr;
        qr = nqr; qi = nqi;

        float gre = cr * qr - ci * qi;
        float gim = cr * qi + ci * qr;
        int o1 = t * 128 + 2 * n, o2 = o1 + 1;
        u16 g1 = f2bf(gre);  Gh[o1] = g1; Gl[o1] = f2bf(gre - bf2f(g1));
        float ngim = -gim;
        u16 g2 = f2bf(ngim); Gh[o2] = g2; Gl[o2] = f2bf(ngim - bf2f(g2));
    }
    if (w == 3) L64[h * 64 + n] = make_float2(qr, qi);   // Lam^64
    __syncthreads();

    const int r = tid >> 2, c0 = (tid & 3) * 16;
    #pragma unroll
    for (int i = 0; i < 16; ++i) {
        int c = c0 + i;
        float val = (c <= r) ? Ksh[r - c] : 0.0f;
        u16 hv = f2bf(val);
        Th[r * 64 + c] = hv; Tl[r * 64 + c] = f2bf(val - bf2f(hv));
    }
}

// ---------------------------------------------------------------------------
// scan5 (measured best): one block per (b,h), 4 waves. Each A-fragment feeds
// 2 column-tiles. LDS: aliased 65 x 512 B buffer. 3 barriers.
// ---------------------------------------------------------------------------
__global__ __launch_bounds__(256, 4) void scan5_kernel(
    const float* __restrict__ u,
    const float* __restrict__ Dg,
    const u16* __restrict__ Phi, const u16* __restrict__ Plo,
    const u16* __restrict__ Ghi, const u16* __restrict__ Glo,
    const u16* __restrict__ Thi, const u16* __restrict__ Tlo,
    const float2* __restrict__ L64,
    float* __restrict__ y)
{
    __shared__ __align__(16) char smem[65 * 512];

    const int bid = blockIdx.x;
    const int b = bid >> 8;
    const int h = ((bid >> 3) & 31) * 8 + (bid & 7);   // same-h blocks share an XCD
    const int tid = threadIdx.x;
    const int w = tid >> 6, l = tid & 63;
    const int l15 = l & 15, lhi = l >> 4;

    const int ctBase  = (w & 1) * 2;
    const int miBaseV = (w >> 1) * 4;
    const int miBaseY = (w >> 1) * 2;

    const float* urow = u + ((size_t)b * HDIM + h) * LDIM;

    // ---- U B-fragments for this wave's 2 col-tiles, direct from global ----
    int cBt[2];
    short8x ubh[2][2], ubl[2][2];                      // [ct2][ks]
    #pragma unroll
    for (int ct2 = 0; ct2 < 2; ++ct2) {
        cBt[ct2] = 16 * (ctBase + ct2) + l15;
        #pragma unroll
        for (int ks = 0; ks < 2; ++ks) {
            const float* src = urow + 64 * cBt[ct2] + 32 * ks + 8 * lhi;
            float4 f0 = *(const float4*)src;
            float4 f1 = *(const float4*)(src + 4);
            float fv[8] = {f0.x, f0.y, f0.z, f0.w, f1.x, f1.y, f1.z, f1.w};
            union { short8x v; u16 s[8]; } H, L;
            #pragma unroll
            for (int q = 0; q < 8; ++q) {
                u16 hq = f2bf(fv[q]);
                H.s[q] = hq; L.s[q] = f2bf(fv[q] - bf2f(hq));
            }
            ubh[ct2][ks] = H.v; ubl[ct2][ks] = L.v;
        }
    }

    // ---- V = P_stack x U : 4 mi x 2 ct per wave ----
    const u16* Ph = Phi + (size_t)h * 8192;
    const u16* Pl = Plo + (size_t)h * 8192;
    {
        f32x4 acc[4][2];
        #pragma unroll
        for (int m = 0; m < 4; ++m)
            #pragma unroll
            for (int c2 = 0; c2 < 2; ++c2)
                acc[m][c2] = (f32x4){0.0f, 0.0f, 0.0f, 0.0f};

        #pragma unroll
        for (int pair = 0; pair < 2; ++pair) {
            short8x pah[2][2], pal[2][2];              // [m][ks]
            #pragma unroll
            for (int m = 0; m < 2; ++m)
                #pragma unroll
                for (int ks = 0; ks < 2; ++ks) {
                    int off = (16 * (miBaseV + 2 * pair + m) + l15) * 64 + 32 * ks + 8 * lhi;
                    pah[m][ks] = *(const short8x*)(Ph + off);
                    pal[m][ks] = *(const short8x*)(Pl + off);
                }
            #pragma unroll
            for (int m = 0; m < 2; ++m)
                #pragma unroll
                for (int ks = 0; ks < 2; ++ks)
                    #pragma unroll
                    for (int c2 = 0; c2 < 2; ++c2) {
                        f32x4 a = acc[2 * pair + m][c2];
                        a = __builtin_amdgcn_mfma_f32_16x16x32_bf16(pah[m][ks], ubh[c2][ks], a, 0, 0, 0);
                        a = __builtin_amdgcn_mfma_f32_16x16x32_bf16(pah[m][ks], ubl[c2][ks], a, 0, 0, 0);
                        a = __builtin_amdgcn_mfma_f32_16x16x32_bf16(pal[m][ks], ubh[c2][ks], a, 0, 0, 0);
                        acc[2 * pair + m][c2] = a;
                    }
        }
        #pragma unroll
        for (int m = 0; m < 4; ++m)
            #pragma unroll
            for (int c2 = 0; c2 < 2; ++c2) {
                int rV = cBt[c2] + 1;
                int byte = 512 * rV + 64 * (miBaseV + m) + 16 * lhi;
                *(f32x4*)(smem + (byte ^ ((rV & 7) << 4))) = acc[m][c2];
            }
    }
    __syncthreads();

    // ---- serial chunk-state scan (wave 0, lane = n), V prefetched ----
    if (w == 0) {
        float2 lt = L64[h * 64 + l];
        float xr = 0.0f, xi = 0.0f;
        float2 v = *(const float2*)(smem + ((512 * 1 + 8 * l) ^ (1 << 4)));
        for (int c = 0; c < NCH; ++c) {
            int rn = (c < 62) ? c + 2 : 64;
            float2 vn = *(const float2*)(smem + ((512 * rn + 8 * l) ^ ((rn & 7) << 4)));
            int sw = (c & 7) << 4;
            u16 hr = f2bf(xr); u16 lr_ = f2bf(xr - bf2f(hr));
            u16 hi_ = f2bf(xi); u16 li_ = f2bf(xi - bf2f(hi_));
            *(u32*)(smem + ((512 * c + 4 * l) ^ sw))       = (u32)hr  | ((u32)hi_ << 16);
            *(u32*)(smem + ((512 * c + 256 + 4 * l) ^ sw)) = (u32)lr_ | ((u32)li_ << 16);
            float nr = fmaf(lt.x, xr, fmaf(-lt.y, xi, v.x));
            float ni = fmaf(lt.x, xi, fmaf( lt.y, xr, v.y));
            xr = nr; xi = ni;
            v = vn;
        }
    }
    __syncthreads();

    // ---- Y = G_stack x X + T x U : 2 mi x 2 ct per wave ----
    const u16* Gh_ = Ghi + (size_t)h * 8192;
    const u16* Gl_ = Glo + (size_t)h * 8192;
    const u16* Th_ = Thi + (size_t)h * 4096;
    const u16* Tl_ = Tlo + (size_t)h * 4096;
    {
        short8x xbh[2][4], xbl[2][4];                  // [ct2][ks]
        #pragma unroll
        for (int c2 = 0; c2 < 2; ++c2) {
            int swX = (cBt[c2] & 7) << 4;
            #pragma unroll
            for (int ks = 0; ks < 4; ++ks) {
                int byte = 512 * cBt[c2] + 64 * ks + 16 * lhi;
                xbh[c2][ks] = *(const short8x*)(smem + (byte ^ swX));
                xbl[c2][ks] = *(const short8x*)(smem + ((byte + 256) ^ swX));
            }
        }
        #pragma unroll
        for (int m = 0; m < 2; ++m) {
            const int mi = miBaseY + m;
            f32x4 acc[2];
            acc[0] = (f32x4){0.0f, 0.0f, 0.0f, 0.0f};
            acc[1] = (f32x4){0.0f, 0.0f, 0.0f, 0.0f};
            short8x gah[4], gal[4], tah[2], tal[2];
            #pragma unroll
            for (int ks = 0; ks < 4; ++ks) {
                int off = (16 * mi + l15) * 128 + 32 * ks + 8 * lhi;
                gah[ks] = *(const short8x*)(Gh_ + off);
                gal[ks] = *(const short8x*)(Gl_ + off);
            }
            #pragma unroll
            for (int ks = 0; ks < 2; ++ks) {
                int off = (16 * mi + l15) * 64 + 32 * ks + 8 * lhi;
                tah[ks] = *(const short8x*)(Th_ + off);
                tal[ks] = *(const short8x*)(Tl_ + off);
            }
            #pragma unroll
            for (int ks = 0; ks < 4; ++ks)
                #pragma unroll
                for (int c2 = 0; c2 < 2; ++c2) {
                    acc[c2] = __builtin_amdgcn_mfma_f32_16x16x32_bf16(gah[ks], xbh[c2][ks], acc[c2], 0, 0, 0);
                    acc[c2] = __builtin_amdgcn_mfma_f32_16x16x32_bf16(gah[ks], xbl[c2][ks], acc[c2], 0, 0, 0);
                    acc[c2] = __builtin_amdgcn_mfma_f32_16x16x32_bf16(gal[ks], xbh[c2][ks], acc[c2], 0, 0, 0);
                }
            #pragma unroll
            for (int ks = 0; ks < 2; ++ks)
                #pragma unroll
                for (int c2 = 0; c2 < 2; ++c2) {
                    acc[c2] = __builtin_amdgcn_mfma_f32_16x16x32_bf16(tah[ks], ubh[c2][ks], acc[c2], 0, 0, 0);
                    acc[c2] = __builtin_amdgcn_mfma_f32_16x16x32_bf16(tah[ks], ubl[c2][ks], acc[c2], 0, 0, 0);
                    acc[c2] = __builtin_amdgcn_mfma_f32_16x16x32_bf16(tal[ks], ubh[c2][ks], acc[c2], 0, 0, 0);
                }
            #pragma unroll
            for (int c2 = 0; c2 < 2; ++c2) {
                int byte = 512 * cBt[c2] + 64 * mi + 16 * lhi;
                *(f32x4*)(smem + (byte ^ ((cBt[c2] & 7) << 4))) = acc[c2];
            }
        }
    }
    __syncthreads();

    // ---- epilogue: y = tanh(Y + D*u), vectorized x4 ----
    const float Dh = Dg[h];
    float* yrow = y + ((size_t)b * HDIM + h) * LDIM;
    #pragma unroll
    for (int k = 0; k < 4; ++k) {
        int g4 = 1024 * k + 4 * tid;
        int c = g4 >> 6, t0 = g4 & 63;
        f32x4 yv = *(const f32x4*)(smem + ((512 * c + 4 * t0) ^ ((c & 7) << 4)));
        float4 uv = *(const float4*)(urow + g4);
        float4 o;
        o.x = tanh_fast(fmaf(Dh, uv.x, yv[0]));
        o.y = tanh_fast(fmaf(Dh, uv.y, yv[1]));
        o.z = tanh_fast(fmaf(Dh, uv.z, yv[2]));
        o.w = tanh_fast(fmaf(Dh, uv.w, yv[3]));
        *(float4*)(yrow + g4) = o;
    }
}

// ---------------------------------------------------------------------------
// W prep: Wp[r][h], r even -> W[r/2] (a-row), r odd -> W[r/2+256] (g-row);
// exact split into bf16 hi + lo, row-major [512][256].
// ---------------------------------------------------------------------------
__global__ __launch_bounds__(256) void prep_w(
    const float* __restrict__ W, u16* __restrict__ Wphi, u16* __restrict__ Wplo)
{
    const int r = blockIdx.x, hcol = threadIdx.x;
    const int src = (r & 1) ? (r >> 1) + 256 : (r >> 1);
    float v = W[src * 256 + hcol];
    u16 hv = f2bf(v);
    Wphi[r * 256 + hcol] = hv;
    Wplo[r * 256 + hcol] = f2bf(v - bf2f(hv));
}

// ---------------------------------------------------------------------------
// mix7: mix4 + DOUBLE-BUFFERED Y staging (T14 split). 512 threads / 8 waves;
// BM=512 rows (wave owns 64 = 4 mi), BN=128 cols (8 ct); K=256 in 4 steps.
// Per kb: issue next-tile global loads -> compute on cur LDS buf -> convert +
// write next buf -> ONE barrier. Buffers alternate => race-free.
// Grid 32 x 8 = 256 blocks (1/CU). In-place on d_out (block-exclusive slice).
// ---------------------------------------------------------------------------
__global__ __launch_bounds__(512, 2) void mix7_kernel(
    const float* y,                        // d_out: scan output [B][256][4096]
    const u16* __restrict__ Wphi, const u16* __restrict__ Wplo,
    const float* __restrict__ bm,
    float* out)                            // d_out (aliases y)
{
    __shared__ __align__(16) u16 Ysh[2][128 * 64];   // 2 x 16 KB

    const int tid = threadIdx.x;
    const int w = tid >> 6, l = tid & 63;
    const int l15 = l & 15, lhi = l >> 4;
    const int b = blockIdx.y;
    const int col0 = blockIdx.x * 128;

    const float* Yb = y + ((size_t)b * HDIM) * LDIM;

    const int p  = tid >> 4;               // k-pair 0..31
    const int cg = tid & 15;               // col-group of 8

    f32x4 acc[4][8];                       // [mi][ct]
    #pragma unroll
    for (int mi = 0; mi < 4; ++mi)
        #pragma unroll
        for (int ct = 0; ct < 8; ++ct)
            acc[mi][ct] = (f32x4){0.0f, 0.0f, 0.0f, 0.0f};

    // ---- prologue: stage kb=0 into buf 0 ----
    {
        const float* r0 = Yb + (size_t)(2 * p) * LDIM + col0 + 8 * cg;
        float4 a0 = *(const float4*)r0;
        float4 a1 = *(const float4*)(r0 + 4);
        float4 b0 = *(const float4*)(r0 + LDIM);
        float4 b1 = *(const float4*)(r0 + LDIM + 4);
        float f0v[8] = {a0.x, a0.y, a0.z, a0.w, a1.x, a1.y, a1.z, a1.w};
        float f1v[8] = {b0.x, b0.y, b0.z, b0.w, b1.x, b1.y, b1.z, b1.w};
        #pragma unroll
        for (int q = 0; q < 8; ++q) {
            int col = 8 * cg + q;
            u32 wv = (u32)f2bf(f0v[q]) | ((u32)f2bf(f1v[q]) << 16);
            int byte = (col * 128 + 4 * p) ^ ((col & 7) << 4);
            *(u32*)((char*)Ysh[0] + byte) = wv;
        }
    }
    __syncthreads();

    for (int kb = 0; kb < 4; ++kb) {
        const int k0 = kb * 64;
        const int cur = kb & 1;

        // ---- issue next K-tile's global loads EARLY ----
        float4 a0, a1, b0, b1;
        if (kb < 3) {
            const float* r0 = Yb + (size_t)(k0 + 64 + 2 * p) * LDIM + col0 + 8 * cg;
            a0 = *(const float4*)r0;
            a1 = *(const float4*)(r0 + 4);
            b0 = *(const float4*)(r0 + LDIM);
            b1 = *(const float4*)(r0 + LDIM + 4);
        }

        // ---- compute on Ysh[cur]: 4 mi x 8 ct ----
        #pragma unroll
        for (int mi = 0; mi < 4; ++mi) {
            const size_t row = (size_t)(64 * w + 16 * mi + l15);
            short8x wh[2], wl[2];
            #pragma unroll
            for (int ks = 0; ks < 2; ++ks) {
                size_t off = row * 256 + k0 + 32 * ks + 8 * lhi;
                wh[ks] = *(const short8x*)(Wphi + off);
                wl[ks] = *(const short8x*)(Wplo + off);
            }
            #pragma unroll
            for (int ct = 0; ct < 8; ++ct) {
                #pragma unroll
                for (int ks = 0; ks < 2; ++ks) {
                    int col = 16 * ct + l15;
                    int byte = (col * 128 + 64 * ks + 16 * lhi) ^ ((col & 7) << 4);
                    short8x yb = *(const short8x*)((char*)Ysh[cur] + byte);
                    acc[mi][ct] = __builtin_amdgcn_mfma_f32_16x16x32_bf16(wh[ks], yb, acc[mi][ct], 0, 0, 0);
                    acc[mi][ct] = __builtin_amdgcn_mfma_f32_16x16x32_bf16(wl[ks], yb, acc[mi][ct], 0, 0, 0);
                }
            }
        }

        // ---- convert + write next buffer (disjoint from cur) ----
        if (kb < 3) {
            float f0v[8] = {a0.x, a0.y, a0.z, a0.w, a1.x, a1.y, a1.z, a1.w};
            float f1v[8] = {b0.x, b0.y, b0.z, b0.w, b1.x, b1.y, b1.z, b1.w};
            #pragma unroll
            for (int q = 0; q < 8; ++q) {
                int col = 8 * cg + q;
                u32 wv = (u32)f2bf(f0v[q]) | ((u32)f2bf(f1v[q]) << 16);
                int byte = (col * 128 + 4 * p) ^ ((col & 7) << 4);
                *(u32*)((char*)Ysh[cur ^ 1] + byte) = wv;
            }
        }
        __syncthreads();
    }

    // ---- epilogue: bias + GLU + store ----
    float* ob = out + ((size_t)b * HDIM) * LDIM;
    #pragma unroll
    for (int mi = 0; mi < 4; ++mi) {
        int r0 = 64 * w + 16 * mi + 4 * lhi;   // multiple of 4
        int h1 = r0 >> 1;
        float ba1 = bm[h1],     bg1 = bm[h1 + 256];
        float ba2 = bm[h1 + 1], bg2 = bm[h1 + 1 + 256];
        #pragma unroll
        for (int ct = 0; ct < 8; ++ct) {
            f32x4 a = acc[mi][ct];
            int col = col0 + 16 * ct + l15;
            float A1 = a[0] + ba1, G1 = a[1] + bg1;
            float A2 = a[2] + ba2, G2 = a[3] + bg2;
            ob[(size_t)h1 * LDIM + col]       = A1 * rcp_fast(1.0f + __expf(-G1));
            ob[(size_t)(h1 + 1) * LDIM + col] = A2 * rcp_fast(1.0f + __expf(-G2));
        }
    }
}

// ---------------------------------------------------------------------------
extern "C" void kernel_launch(void* const* d_in, const int* in_sizes, int n_in,
                              void* d_out, int out_size, void* d_ws, size_t ws_size,
                              hipStream_t stream)
{
    const float* u    = (const float*)d_in[0];
    const float* lre  = (const float*)d_in[1];
    const float* lim  = (const float*)d_in[2];
    const float* cbre = (const float*)d_in[3];
    const float* cbim = (const float*)d_in[4];
    const float* Dg   = (const float*)d_in[5];
    const float* W    = (const float*)d_in[6];
    const float* bm   = (const float*)d_in[7];
    float* out = (float*)d_out;

    char* ws = (char*)d_ws;
    size_t o = 0;
    u16* Wphi = (u16*)(ws + o); o += (size_t)1 << 18;      // 256 KB
    u16* Wplo = (u16*)(ws + o); o += (size_t)1 << 18;      // 256 KB
    u16* Phi = (u16*)(ws + o); o += (size_t)1 << 22;       // 4 MB each
    u16* Plo = (u16*)(ws + o); o += (size_t)1 << 22;
    u16* Ghi = (u16*)(ws + o); o += (size_t)1 << 22;
    u16* Glo = (u16*)(ws + o); o += (size_t)1 << 22;
    u16* Thi = (u16*)(ws + o); o += (size_t)1 << 21;       // 2 MB each
    u16* Tlo = (u16*)(ws + o); o += (size_t)1 << 21;
    float2* L64 = (float2*)(ws + o);                       // 128 KB

    tables3_kernel<<<HDIM, 256, 0, stream>>>(lre, lim, cbre, cbim,
                                             Phi, Plo, Ghi, Glo, Thi, Tlo, L64);
    prep_w<<<512, 256, 0, stream>>>(W, Wphi, Wplo);
    scan5_kernel<<<BDIM * HDIM, 256, 0, stream>>>(u, Dg, Phi, Plo, Ghi, Glo,
                                                  Thi, Tlo, L64, out);
    dim3 grid(LDIM / 128, BDIM);
    mix7_kernel<<<grid, 512, 0, stream>>>(out, Wphi, Wplo, bm, out);
}